// Round 1
// baseline (693.674 us; speedup 1.0000x reference)
//
#include <hip/hip_runtime.h>

#define N_PTS 20000
#define KNN 16
#define C 256
#define G 16
#define EPS 1e-5f

__device__ inline unsigned short f2bf(float f) {
    unsigned int x = __float_as_uint(f);
    unsigned int r = (x + 0x7fffu + ((x >> 16) & 1u)) >> 16;
    return (unsigned short)r;
}
__device__ inline float bf2f(unsigned int u) {
    return __uint_as_float((u & 0xffffu) << 16);
}

// ---------------- K0: Wp2w1[d][g] = sum_c Wp2[d][c]*Ww1[c][g]; c1[g] = bp2@Ww1 + bw1
__global__ __launch_bounds__(256) void k_prep(const float* Wp2, const float* bp2,
                                              const float* Ww1, const float* bw1,
                                              float* w2w1, float* c1) {
    __shared__ float red[256][17];
    int t = threadIdx.x, b = blockIdx.x;
    float src = (b < C) ? Wp2[b * C + t] : bp2[t];
    #pragma unroll
    for (int g = 0; g < G; ++g) red[t][g] = src * Ww1[t * G + g];
    __syncthreads();
    for (int s = 128; s > 0; s >>= 1) {
        if (t < s) {
            #pragma unroll
            for (int g = 0; g < G; ++g) red[t][g] += red[t + s][g];
        }
        __syncthreads();
    }
    if (t < G) {
        if (b < C) w2w1[b * G + t] = red[0][t];
        else       c1[t] = red[0][t] + bw1[t];
    }
}

// ---------------- K1: q/k/v = feat @ W (+bias, +BN+ReLU for q,k). 128x128 tile, 8x8/thread
#define BM 128
#define BN 128
#define BK 16
__global__ __launch_bounds__(256) void k_qkv(
    const float* feat, const float* Wq, const float* bq, const float* bnq,
    const float* Wk, const float* bk, const float* bnk,
    const float* Wv, const float* bv,
    float* q_out, float* k_out, float* v_out) {
    __shared__ float As[BK][BM + 4];
    __shared__ float Bs[BK][BN + 4];
    int t = threadIdx.x;
    int m0 = blockIdx.x * BM;
    int n0 = blockIdx.y * BN;
    int z = blockIdx.z;
    const float* W    = (z == 0) ? Wq : (z == 1) ? Wk : Wv;
    const float* bias = (z == 0) ? bq : (z == 1) ? bk : bv;
    const float* bn   = (z == 0) ? bnq : bnk;   // unused for z==2

    int tx = t & 15, ty = t >> 4;
    float acc[8][8] = {};
    int arow = t >> 2, ac4 = (t & 3) * 4;
    int brow = t >> 5, bc = (t & 31) * 4;

    for (int kb = 0; kb < C; kb += BK) {
        #pragma unroll
        for (int p = 0; p < 2; ++p) {
            int r = arow + p * 64;
            int gr = m0 + r; if (gr > N_PTS - 1) gr = N_PTS - 1;
            float4 f = *(const float4*)&feat[gr * C + kb + ac4];
            As[ac4 + 0][r] = f.x; As[ac4 + 1][r] = f.y;
            As[ac4 + 2][r] = f.z; As[ac4 + 3][r] = f.w;
        }
        #pragma unroll
        for (int p = 0; p < 2; ++p) {
            int kr = brow + p * 8;
            *(float4*)&Bs[kr][bc] = *(const float4*)&W[(kb + kr) * C + n0 + bc];
        }
        __syncthreads();
        #pragma unroll
        for (int kk = 0; kk < BK; ++kk) {
            float4 a0 = *(float4*)&As[kk][ty * 8];
            float4 a1 = *(float4*)&As[kk][ty * 8 + 4];
            float4 b0 = *(float4*)&Bs[kk][tx * 8];
            float4 b1 = *(float4*)&Bs[kk][tx * 8 + 4];
            float av[8] = {a0.x, a0.y, a0.z, a0.w, a1.x, a1.y, a1.z, a1.w};
            float bw[8] = {b0.x, b0.y, b0.z, b0.w, b1.x, b1.y, b1.z, b1.w};
            #pragma unroll
            for (int i = 0; i < 8; ++i) {
                #pragma unroll
                for (int j = 0; j < 8; ++j) acc[i][j] += av[i] * bw[j];
            }
        }
        __syncthreads();
    }
    int cbase = n0 + tx * 8;
    float sc[8], sh[8];
    #pragma unroll
    for (int j = 0; j < 8; ++j) {
        int c = cbase + j;
        float bi = bias[c];
        if (z < 2) {
            float ga = bn[c], be = bn[C + c], mu = bn[2 * C + c], va = bn[3 * C + c];
            float s = ga * rsqrtf(va + EPS);
            sc[j] = s; sh[j] = (bi - mu) * s + be;
        } else { sc[j] = 1.f; sh[j] = bi; }
    }
    float* dst = (z == 0) ? q_out : (z == 1) ? k_out : v_out;
    #pragma unroll
    for (int i = 0; i < 8; ++i) {
        int m = m0 + ty * 8 + i;
        if (m >= N_PTS) continue;
        float o[8];
        #pragma unroll
        for (int j = 0; j < 8; ++j) {
            float x = acc[i][j] * sc[j] + sh[j];
            o[j] = (z < 2) ? fmaxf(x, 0.f) : x;
        }
        *(float4*)&dst[m * C + cbase]     = make_float4(o[0], o[1], o[2], o[3]);
        *(float4*)&dst[m * C + cbase + 4] = make_float4(o[4], o[5], o[6], o[7]);
    }
}

// ---------------- K2: qw1 = q @ Ww1, kw1 = k @ Ww1  (N x 16 each)
__global__ __launch_bounds__(256) void k_qkw(const float* q_ws, const float* k_ws,
                                             const float* Ww1, float* qw1, float* kw1) {
    __shared__ float tile[16][260];
    __shared__ float wT[G][260];
    int t = threadIdx.x;
    const float* src = blockIdx.y ? k_ws : q_ws;
    float* dst = blockIdx.y ? kw1 : qw1;
    int r0 = blockIdx.x * 16;
    #pragma unroll
    for (int i = 0; i < 16; ++i) {
        int e = t + 256 * i;                 // 4096 elems of Ww1 (c*16+g)
        wT[e & 15][e >> 4] = Ww1[e];
    }
    #pragma unroll
    for (int i = 0; i < 4; ++i) {
        int e4 = t + 256 * i;                // 1024 float4s
        int row = e4 >> 6, col = (e4 & 63) * 4;
        *(float4*)&tile[row][col] = *(const float4*)&src[(r0 + row) * C + col];
    }
    __syncthreads();
    int r = t >> 4, g = t & 15;
    float acc = 0.f;
    for (int c = 0; c < C; c += 4) {
        float4 a = *(float4*)&tile[r][c];
        float4 w = *(float4*)&wT[g][c];
        acc += a.x * w.x + a.y * w.y + a.z * w.z + a.w * w.w;
    }
    dst[(r0 + r) * G + g] = acc;
}

// ---------------- K3: per 2 points -> softmax weights wt (N,K,G)
__global__ __launch_bounds__(256) void k_weights(
    const float* coord, const int* knn, const float* Wp1, const float* bp1,
    const float* bnp, const float* Ww2, const float* bw2, const float* bnw,
    const float* w2w1, const float* c1, const float* qw1, const float* kw1,
    float* wt_out) {
    __shared__ float posm[32][4];
    __shared__ int   safe_s[32];
    __shared__ float Hs[32][260];
    __shared__ float W2s[C * G];
    __shared__ float w1s[32][16];
    __shared__ float w2s[32][17];
    __shared__ float Ww2s[256];
    __shared__ float scw[16], shw[16], bw2s[16], c1s[16];
    __shared__ float offs[32][16];
    int t = threadIdx.x;
    int n0 = blockIdx.x * 2;

    #pragma unroll
    for (int i = 0; i < 16; ++i) W2s[t + 256 * i] = w2w1[t + 256 * i];
    Ww2s[t & 255] = Ww2[t & 255];
    if (t < 16) {
        float ga = bnw[t], be = bnw[G + t], mu = bnw[2 * G + t], va = bnw[3 * G + t];
        float s = ga * rsqrtf(va + EPS);
        scw[t] = s; shw[t] = be - mu * s;
        bw2s[t] = bw2[t]; c1s[t] = c1[t];
    }
    if (t < 32) {
        int p = t >> 4, n = n0 + p;
        int ii = knn[n * KNN + (t & 15)];
        float mk = (ii >= 0) ? 1.f : 0.f;
        int safe = ii < 0 ? 0 : ii;
        safe_s[t] = safe;
        posm[t][0] = (coord[safe * 3]     - coord[n * 3])     * mk;
        posm[t][1] = (coord[safe * 3 + 1] - coord[n * 3 + 1]) * mk;
        posm[t][2] = (coord[safe * 3 + 2] - coord[n * 3 + 2]) * mk;
        posm[t][3] = mk;
    }
    __syncthreads();
    {   // phase A: H[r][d=t]
        float w0 = Wp1[t], w1_ = Wp1[C + t], w2_ = Wp1[2 * C + t], bp = bp1[t];
        float ga = bnp[t], be = bnp[C + t], mu = bnp[2 * C + t], va = bnp[3 * C + t];
        float s = ga * rsqrtf(va + EPS), sh = be - mu * s;
        for (int r = 0; r < 32; ++r) {
            float4 pm = *(float4*)&posm[r][0];
            float x = pm.x * w0 + pm.y * w1_ + pm.z * w2_ + bp;
            Hs[r][t] = fmaxf(x * s + sh, 0.f);
        }
    }
    if (t < 32) {
        int n = n0 + (t >> 4);
        float mk = posm[t][3];
        int safe = safe_s[t];
        #pragma unroll
        for (int g = 0; g < G; ++g)
            offs[t][g] = kw1[safe * G + g] * mk - qw1[n * G + g] + c1s[g];
    }
    __syncthreads();
    {   // phase B: w1 = H @ W2w1 + offs, then BN+ReLU
        int r = t >> 3, g0 = (t & 7) * 2;
        float a0 = offs[r][g0], a1 = offs[r][g0 + 1];
        for (int d = 0; d < C; d += 4) {
            float4 h = *(float4*)&Hs[r][d];
            float2 wa = *(float2*)&W2s[(d + 0) * G + g0];
            float2 wb = *(float2*)&W2s[(d + 1) * G + g0];
            float2 wc = *(float2*)&W2s[(d + 2) * G + g0];
            float2 wd = *(float2*)&W2s[(d + 3) * G + g0];
            a0 += h.x * wa.x + h.y * wb.x + h.z * wc.x + h.w * wd.x;
            a1 += h.x * wa.y + h.y * wb.y + h.z * wc.y + h.w * wd.y;
        }
        w1s[r][g0]     = fmaxf(a0 * scw[g0]     + shw[g0],     0.f);
        w1s[r][g0 + 1] = fmaxf(a1 * scw[g0 + 1] + shw[g0 + 1], 0.f);
    }
    __syncthreads();
    {   // phase C: w2 = w1 @ Ww2 + bw2
        int r = t >> 3, g0 = (t & 7) * 2;
        float a0 = bw2s[g0], a1 = bw2s[g0 + 1];
        #pragma unroll
        for (int gp = 0; gp < G; ++gp) {
            float x = w1s[r][gp];
            float2 w = *(float2*)&Ww2s[gp * G + g0];
            a0 += x * w.x; a1 += x * w.y;
        }
        w2s[r][g0] = a0; w2s[r][g0 + 1] = a1;
    }
    __syncthreads();
    if (t < 32) {   // softmax over k per (p,g), then *mask
        int p = t >> 4, g = t & 15;
        float m = -1e30f;
        #pragma unroll
        for (int k = 0; k < KNN; ++k) m = fmaxf(m, w2s[p * 16 + k][g]);
        float e[KNN], s = 0.f;
        #pragma unroll
        for (int k = 0; k < KNN; ++k) { e[k] = __expf(w2s[p * 16 + k][g] - m); s += e[k]; }
        float inv = 1.f / s;
        #pragma unroll
        for (int k = 0; k < KNN; ++k)
            wt_out[((n0 + p) * KNN + k) * G + g] = e[k] * inv * posm[p * 16 + k][3];
    }
}

// ---------------- K4: out = sum_k wt*(v_g + H@Wp2 + bp2), via Hw = sum_k wt*H (group-diag)
__global__ __launch_bounds__(256) void k_out(
    const float* coord, const int* knn, const float* Wp1, const float* bp1,
    const float* bnp, const float* Wp2, const float* bp2,
    const float* v_ws, const float* wt_ws, float* out) {
    __shared__ float posm[32][4];
    __shared__ int   safe_s[32];
    __shared__ unsigned short Hs[32][264];
    __shared__ unsigned short Hw[32][264];
    __shared__ float wts[32][20];
    __shared__ float wp2t[256][36];
    int t = threadIdx.x;
    int n0 = blockIdx.x * 2;

    if (t < 32) {
        int p = t >> 4, n = n0 + p;
        int ii = knn[n * KNN + (t & 15)];
        float mk = (ii >= 0) ? 1.f : 0.f;
        int safe = ii < 0 ? 0 : ii;
        safe_s[t] = safe;
        posm[t][0] = (coord[safe * 3]     - coord[n * 3])     * mk;
        posm[t][1] = (coord[safe * 3 + 1] - coord[n * 3 + 1]) * mk;
        posm[t][2] = (coord[safe * 3 + 2] - coord[n * 3 + 2]) * mk;
        posm[t][3] = mk;
    }
    #pragma unroll
    for (int i = 0; i < 2; ++i) {
        int e = t + 256 * i;                 // 512 = 32 rows x 16 g
        wts[e >> 4][e & 15] = wt_ws[n0 * KNN * G + e];
    }
    __syncthreads();
    {   // recompute H (bf16)
        float w0 = Wp1[t], w1_ = Wp1[C + t], w2_ = Wp1[2 * C + t], bp = bp1[t];
        float ga = bnp[t], be = bnp[C + t], mu = bnp[2 * C + t], va = bnp[3 * C + t];
        float s = ga * rsqrtf(va + EPS), sh = be - mu * s;
        for (int r = 0; r < 32; ++r) {
            float4 pm = *(float4*)&posm[r][0];
            float x = pm.x * w0 + pm.y * w1_ + pm.z * w2_ + bp;
            Hs[r][t] = f2bf(fmaxf(x * s + sh, 0.f));
        }
    }
    __syncthreads();
    // phase D: Hw[p*16+g][d=t] = sum_k wt[p][k][g]*H[p*16+k][t]
    #pragma unroll
    for (int p = 0; p < 2; ++p) {
        float hr[16];
        #pragma unroll
        for (int k = 0; k < 16; ++k) hr[k] = bf2f(Hs[p * 16 + k][t]);
        #pragma unroll
        for (int g4 = 0; g4 < 4; ++g4) {
            float a0 = 0, a1 = 0, a2 = 0, a3 = 0;
            #pragma unroll
            for (int k = 0; k < 16; ++k) {
                float4 w = *(float4*)&wts[p * 16 + k][g4 * 4];
                a0 += hr[k] * w.x; a1 += hr[k] * w.y;
                a2 += hr[k] * w.z; a3 += hr[k] * w.w;
            }
            Hw[p * 16 + g4 * 4 + 0][t] = f2bf(a0);
            Hw[p * 16 + g4 * 4 + 1][t] = f2bf(a1);
            Hw[p * 16 + g4 * 4 + 2][t] = f2bf(a2);
            Hw[p * 16 + g4 * 4 + 3][t] = f2bf(a3);
        }
    }
    __syncthreads();
    // phase E: out_peb[p][c] = Hw[p,g(c)] . Wp2[:,c]   (staged transposed chunks)
    int c = t, g = t >> 4;
    float accp0 = 0.f, accp1 = 0.f;
    for (int dc = 0; dc < C; dc += 32) {
        #pragma unroll
        for (int dr = 0; dr < 32; ++dr)
            wp2t[t][dr] = Wp2[(dc + dr) * C + c];
        __syncthreads();
        #pragma unroll
        for (int p = 0; p < 2; ++p) {
            float a = 0.f;
            #pragma unroll
            for (int d = 0; d < 32; d += 4) {
                uint2 hb = *(uint2*)&Hw[p * 16 + g][dc + d];
                float4 wv = *(float4*)&wp2t[c][d];
                a += bf2f(hb.x) * wv.x + bf2f(hb.x >> 16) * wv.y
                   + bf2f(hb.y) * wv.z + bf2f(hb.y >> 16) * wv.w;
            }
            if (p == 0) accp0 += a; else accp1 += a;
        }
        __syncthreads();
    }
    // phase V: v-gather weighted sum + bp2 term
    float bp2c = bp2[c];
    #pragma unroll
    for (int p = 0; p < 2; ++p) {
        float ov = 0.f, wsum = 0.f;
        #pragma unroll
        for (int k = 0; k < KNN; ++k) {
            float w = wts[p * 16 + k][g];
            wsum += w;
            ov += w * v_ws[safe_s[p * 16 + k] * C + c];
        }
        float peb = (p == 0) ? accp0 : accp1;
        out[(n0 + p) * C + c] = peb + ov + wsum * bp2c;
    }
}

extern "C" void kernel_launch(void* const* d_in, const int* in_sizes, int n_in,
                              void* d_out, int out_size, void* d_ws, size_t ws_size,
                              hipStream_t stream) {
    const float* feat  = (const float*)d_in[0];
    const float* coord = (const float*)d_in[1];
    const int*   knn   = (const int*)d_in[2];
    const float* Wq  = (const float*)d_in[3];
    const float* bq  = (const float*)d_in[4];
    const float* bnq = (const float*)d_in[5];
    const float* Wk  = (const float*)d_in[6];
    const float* bk  = (const float*)d_in[7];
    const float* bnk = (const float*)d_in[8];
    const float* Wv  = (const float*)d_in[9];
    const float* bv  = (const float*)d_in[10];
    const float* Wp1 = (const float*)d_in[11];
    const float* bp1 = (const float*)d_in[12];
    const float* bnp = (const float*)d_in[13];
    const float* Wp2 = (const float*)d_in[14];
    const float* bp2 = (const float*)d_in[15];
    const float* Ww1 = (const float*)d_in[16];
    const float* bw1 = (const float*)d_in[17];
    const float* bnw = (const float*)d_in[18];
    const float* Ww2 = (const float*)d_in[19];
    const float* bw2 = (const float*)d_in[20];

    float* ws    = (float*)d_ws;
    float* q_ws  = ws;
    float* k_ws  = ws + 5120000;
    float* v_ws  = ws + 10240000;
    float* qw1   = ws + 15360000;
    float* kw1   = ws + 15760000;
    float* w2w1  = ws + 16160000;
    float* c1    = ws + 16164096;
    float* wt_ws = ws + 16164112;
    float* outp  = (float*)d_out;

    hipLaunchKernelGGL(k_prep, dim3(257), dim3(256), 0, stream,
                       Wp2, bp2, Ww1, bw1, w2w1, c1);
    hipLaunchKernelGGL(k_qkv, dim3(157, 2, 3), dim3(256), 0, stream,
                       feat, Wq, bq, bnq, Wk, bk, bnk, Wv, bv, q_ws, k_ws, v_ws);
    hipLaunchKernelGGL(k_qkw, dim3(1250, 2), dim3(256), 0, stream,
                       q_ws, k_ws, Ww1, qw1, kw1);
    hipLaunchKernelGGL(k_weights, dim3(10000), dim3(256), 0, stream,
                       coord, knn, Wp1, bp1, bnp, Ww2, bw2, bnw, w2w1, c1, qw1, kw1, wt_ws);
    hipLaunchKernelGGL(k_out, dim3(10000), dim3(256), 0, stream,
                       coord, knn, Wp1, bp1, bnp, Wp2, bp2, v_ws, wt_ws, outp);
}

// Round 3
// 468.718 us; speedup vs baseline: 1.4799x; 1.4799x over previous
//
#include <hip/hip_runtime.h>

#define N_PTS 20000
#define KNN 16
#define C 256
#define G 16
#define EPS 1e-5f
#define NP 32
#define ROWS 512
#define DE_CH 32
#define NCH 8

__device__ inline unsigned short f2bf(float f) {
    unsigned int x = __float_as_uint(f);
    unsigned int r = (x + 0x7fffu + ((x >> 16) & 1u)) >> 16;
    return (unsigned short)r;
}
__device__ inline float bf2f(unsigned int u) {
    return __uint_as_float((u & 0xffffu) << 16);
}

// ---------------- K0: w2w1[d][g] = sum_c Wp2[d][c]*Ww1[c][g]; c1[g] = bp2@Ww1 + bw1
__global__ __launch_bounds__(256) void k_prep(const float* Wp2, const float* bp2,
                                              const float* Ww1, const float* bw1,
                                              float* w2w1, float* c1) {
    __shared__ float red[256][17];
    int t = threadIdx.x, b = blockIdx.x;
    float src = (b < C) ? Wp2[b * C + t] : bp2[t];
    #pragma unroll
    for (int g = 0; g < G; ++g) red[t][g] = src * Ww1[t * G + g];
    __syncthreads();
    for (int s = 128; s > 0; s >>= 1) {
        if (t < s) {
            #pragma unroll
            for (int g = 0; g < G; ++g) red[t][g] += red[t + s][g];
        }
        __syncthreads();
    }
    if (t < G) {
        if (b < C) w2w1[b * G + t] = red[0][t];
        else       c1[t] = red[0][t] + bw1[t];
    }
}

// ---------------- K1: q/k/v = feat @ W (+bias, +BN+ReLU for q,k; v -> bf16)
#define BM 128
#define BN 128
#define BK 16
__global__ __launch_bounds__(256) void k_qkv(
    const float* feat, const float* Wq, const float* bq, const float* bnq,
    const float* Wk, const float* bk, const float* bnk,
    const float* Wv, const float* bv,
    float* q_out, float* k_out, unsigned short* v_out) {
    __shared__ float As[BK][BM + 4];
    __shared__ float Bs[BK][BN + 4];
    int t = threadIdx.x;
    int m0 = blockIdx.x * BM;
    int n0 = blockIdx.y * BN;
    int z = blockIdx.z;
    const float* W    = (z == 0) ? Wq : (z == 1) ? Wk : Wv;
    const float* bias = (z == 0) ? bq : (z == 1) ? bk : bv;
    const float* bn   = (z == 0) ? bnq : bnk;

    int tx = t & 15, ty = t >> 4;
    float acc[8][8] = {};
    int arow = t >> 2, ac4 = (t & 3) * 4;
    int brow = t >> 5, bc = (t & 31) * 4;

    for (int kb = 0; kb < C; kb += BK) {
        #pragma unroll
        for (int p = 0; p < 2; ++p) {
            int r = arow + p * 64;
            int gr = m0 + r; if (gr > N_PTS - 1) gr = N_PTS - 1;
            float4 f = *(const float4*)&feat[gr * C + kb + ac4];
            As[ac4 + 0][r] = f.x; As[ac4 + 1][r] = f.y;
            As[ac4 + 2][r] = f.z; As[ac4 + 3][r] = f.w;
        }
        #pragma unroll
        for (int p = 0; p < 2; ++p) {
            int kr = brow + p * 8;
            *(float4*)&Bs[kr][bc] = *(const float4*)&W[(kb + kr) * C + n0 + bc];
        }
        __syncthreads();
        #pragma unroll
        for (int kk = 0; kk < BK; ++kk) {
            float4 a0 = *(float4*)&As[kk][ty * 8];
            float4 a1 = *(float4*)&As[kk][ty * 8 + 4];
            float4 b0 = *(float4*)&Bs[kk][tx * 8];
            float4 b1 = *(float4*)&Bs[kk][tx * 8 + 4];
            float av[8] = {a0.x, a0.y, a0.z, a0.w, a1.x, a1.y, a1.z, a1.w};
            float bw[8] = {b0.x, b0.y, b0.z, b0.w, b1.x, b1.y, b1.z, b1.w};
            #pragma unroll
            for (int i = 0; i < 8; ++i) {
                #pragma unroll
                for (int j = 0; j < 8; ++j) acc[i][j] += av[i] * bw[j];
            }
        }
        __syncthreads();
    }
    int cbase = n0 + tx * 8;
    float sc[8], sh[8];
    #pragma unroll
    for (int j = 0; j < 8; ++j) {
        int c = cbase + j;
        float bi = bias[c];
        if (z < 2) {
            float ga = bn[c], be = bn[C + c], mu = bn[2 * C + c], va = bn[3 * C + c];
            float s = ga * rsqrtf(va + EPS);
            sc[j] = s; sh[j] = (bi - mu) * s + be;
        } else { sc[j] = 1.f; sh[j] = bi; }
    }
    #pragma unroll
    for (int i = 0; i < 8; ++i) {
        int m = m0 + ty * 8 + i;
        if (m >= N_PTS) continue;
        float o[8];
        #pragma unroll
        for (int j = 0; j < 8; ++j) {
            float x = acc[i][j] * sc[j] + sh[j];
            o[j] = (z < 2) ? fmaxf(x, 0.f) : x;
        }
        if (z < 2) {
            float* dst = (z == 0) ? q_out : k_out;
            *(float4*)&dst[m * C + cbase]     = make_float4(o[0], o[1], o[2], o[3]);
            *(float4*)&dst[m * C + cbase + 4] = make_float4(o[4], o[5], o[6], o[7]);
        } else {
            unsigned int p0 = f2bf(o[0]) | ((unsigned int)f2bf(o[1]) << 16);
            unsigned int p1 = f2bf(o[2]) | ((unsigned int)f2bf(o[3]) << 16);
            unsigned int p2 = f2bf(o[4]) | ((unsigned int)f2bf(o[5]) << 16);
            unsigned int p3 = f2bf(o[6]) | ((unsigned int)f2bf(o[7]) << 16);
            *(uint4*)&v_out[m * C + cbase] = make_uint4(p0, p1, p2, p3);
        }
    }
}

// ---------------- K2: qw1 = q @ Ww1, kw1 = k @ Ww1  (N x 16 each)
__global__ __launch_bounds__(256) void k_qkw(const float* q_ws, const float* k_ws,
                                             const float* Ww1, float* qw1, float* kw1) {
    __shared__ float tile[16][260];
    __shared__ float wT[G][260];
    int t = threadIdx.x;
    const float* src = blockIdx.y ? k_ws : q_ws;
    float* dst = blockIdx.y ? kw1 : qw1;
    int r0 = blockIdx.x * 16;
    #pragma unroll
    for (int i = 0; i < 16; ++i) {
        int e = t + 256 * i;
        wT[e & 15][e >> 4] = Ww1[e];
    }
    #pragma unroll
    for (int i = 0; i < 4; ++i) {
        int e4 = t + 256 * i;
        int row = e4 >> 6, col = (e4 & 63) * 4;
        *(float4*)&tile[row][col] = *(const float4*)&src[(r0 + row) * C + col];
    }
    __syncthreads();
    int r = t >> 4, g = t & 15;
    float acc = 0.f;
    for (int c = 0; c < C; c += 4) {
        float4 a = *(float4*)&tile[r][c];
        float4 w = *(float4*)&wT[g][c];
        acc += a.x * w.x + a.y * w.y + a.z * w.z + a.w * w.w;
    }
    dst[(r0 + r) * G + g] = acc;
}

// ---------------- K3: fused attention: weights + output, 32 points/block
__global__ __launch_bounds__(512, 2) void k_attn(
    const float* __restrict__ coord, const int* __restrict__ knn,
    const float* __restrict__ Wp1, const float* __restrict__ bp1, const float* __restrict__ bnp,
    const float* __restrict__ Wp2, const float* __restrict__ bp2,
    const float* __restrict__ Ww2, const float* __restrict__ bw2, const float* __restrict__ bnw,
    const float* __restrict__ w2w1, const float* __restrict__ c1,
    const float* __restrict__ qw1, const float* __restrict__ kw1,
    const unsigned short* __restrict__ vb, float* __restrict__ out)
{
    __shared__ float posm[ROWS][4];          // 8 KB
    __shared__ int   safe_s[ROWS];           // 2 KB
    __shared__ float W2w1s[C][G];            // 16 KB [d][g]
    __shared__ float Ww2s[G][G];             // 1 KB
    __shared__ float wp1c[C][4];             // 4 KB  w0*s, w1*s, w2*s, sh
    __shared__ float scw_s[G], shw_s[G], bw2_s[G], c1_s[G];
    __shared__ unsigned short Hs[ROWS][36];  // 36 KB  H chunk (bf16)
    __shared__ unsigned short Hws[ROWS][36]; // 36 KB  Hw chunk (bf16)
    __shared__ float w2s[ROWS][17];          // 34 KB  logits -> wt (in place)

    const int t = threadIdx.x;
    const int n0 = blockIdx.x * NP;

    // ---- stage constants
    for (int i = t; i < C * G; i += 512) W2w1s[i >> 4][i & 15] = w2w1[i];
    if (t < C) {
        float ga = bnp[t], be = bnp[C + t], mu = bnp[2 * C + t], va = bnp[3 * C + t];
        float s = ga * rsqrtf(va + EPS);
        wp1c[t][0] = Wp1[t] * s;
        wp1c[t][1] = Wp1[C + t] * s;
        wp1c[t][2] = Wp1[2 * C + t] * s;
        wp1c[t][3] = (bp1[t] - mu) * s + be;
    } else {
        int i = t - 256;
        Ww2s[i >> 4][i & 15] = Ww2[i];
    }
    if (t < G) {
        float ga = bnw[t], be = bnw[G + t], mu = bnw[2 * G + t], va = bnw[3 * G + t];
        float s = ga * rsqrtf(va + EPS);
        scw_s[t] = s; shw_s[t] = be - mu * s;
        bw2_s[t] = bw2[t]; c1_s[t] = c1[t];
    }
    // ---- phase A: pos/mask/safe (thread = neighbor row)
    const int row = t;
    const int n = n0 + (row >> 4);
    int ii = knn[n * KNN + (row & 15)];
    float mk = (ii >= 0) ? 1.f : 0.f;
    int safe = ii < 0 ? 0 : ii;
    safe_s[row] = safe;
    float px = (coord[safe * 3]     - coord[n * 3])     * mk;
    float py = (coord[safe * 3 + 1] - coord[n * 3 + 1]) * mk;
    float pz = (coord[safe * 3 + 2] - coord[n * 3 + 2]) * mk;
    posm[row][0] = px; posm[row][1] = py; posm[row][2] = pz; posm[row][3] = mk;
    __syncthreads();

    // ---- offs[g] = kw1[safe]*mk - qw1[n] + c1
    float offs[16];
    {
        const float4* kwp = (const float4*)&kw1[safe * G];
        const float4* qwp = (const float4*)&qw1[n * G];
        #pragma unroll
        for (int j = 0; j < 4; ++j) {
            float4 kv = kwp[j], qv = qwp[j];
            offs[4 * j + 0] = kv.x * mk - qv.x + c1_s[4 * j + 0];
            offs[4 * j + 1] = kv.y * mk - qv.y + c1_s[4 * j + 1];
            offs[4 * j + 2] = kv.z * mk - qv.z + c1_s[4 * j + 2];
            offs[4 * j + 3] = kv.w * mk - qv.w + c1_s[4 * j + 3];
        }
    }
    // ---- phase B: w1acc[g] = sum_d H[row][d] * W2w1[d][g]  (H in flight, never stored)
    float w1acc[16] = {};
    #pragma unroll 4
    for (int d = 0; d < C; ++d) {
        float4 cc = *(const float4*)&wp1c[d][0];
        float h = fmaxf(px * cc.x + py * cc.y + pz * cc.z + cc.w, 0.f);
        const float4* wr = (const float4*)&W2w1s[d][0];
        #pragma unroll
        for (int j = 0; j < 4; ++j) {
            float4 w = wr[j];
            w1acc[4 * j + 0] += h * w.x;
            w1acc[4 * j + 1] += h * w.y;
            w1acc[4 * j + 2] += h * w.z;
            w1acc[4 * j + 3] += h * w.w;
        }
    }
    // BN+ReLU, then phase C: w2 = w1 @ Ww2 + bw2
    float w1v[16], w2v[16];
    #pragma unroll
    for (int g2 = 0; g2 < 16; ++g2) {
        w1v[g2] = fmaxf(scw_s[g2] * (w1acc[g2] + offs[g2]) + shw_s[g2], 0.f);
        w2v[g2] = bw2_s[g2];
    }
    #pragma unroll
    for (int g2 = 0; g2 < 16; ++g2) {
        float x = w1v[g2];
        const float4* wr = (const float4*)&Ww2s[g2][0];
        #pragma unroll
        for (int j = 0; j < 4; ++j) {
            float4 w = wr[j];
            w2v[4 * j + 0] += x * w.x;
            w2v[4 * j + 1] += x * w.y;
            w2v[4 * j + 2] += x * w.z;
            w2v[4 * j + 3] += x * w.w;
        }
    }
    #pragma unroll
    for (int g2 = 0; g2 < 16; ++g2) w2s[row][g2] = w2v[g2];
    __syncthreads();

    // ---- softmax over k per (p,g); wt stays in regs AND goes to w2s in place
    const int p = t >> 4, g = t & 15;
    const int rb = p * 16;
    float wt_reg[16];
    {
        float m = -1e30f;
        #pragma unroll
        for (int k = 0; k < KNN; ++k) { float x = w2s[rb + k][g]; wt_reg[k] = x; m = fmaxf(m, x); }
        float s = 0.f;
        #pragma unroll
        for (int k = 0; k < KNN; ++k) { float e = __expf(wt_reg[k] - m); wt_reg[k] = e; s += e; }
        float inv = 1.f / s;
        #pragma unroll
        for (int k = 0; k < KNN; ++k) {
            wt_reg[k] = wt_reg[k] * inv * posm[rb + k][3];
            w2s[rb + k][g] = wt_reg[k];
        }
    }

    // ---- chunked D (Hw) + E (peb) ; thread roles: row / (p,g) / (c,ph)
    const int c = t & 255, ph = t >> 8, gc = c >> 4;
    float acc[16] = {};
    float bp2c = bp2[c];

    for (int ch = 0; ch < NCH; ++ch) {
        const int d0 = ch * DE_CH;
        if (ch) __syncthreads();   // prev (b) done with Hs, prev (c) done with Hws
        // (a) recompute H chunk -> Hs (bf16), thread = row
        {
            uint2* hp = (uint2*)&Hs[row][0];
            #pragma unroll
            for (int j = 0; j < 8; ++j) {
                int d = d0 + 4 * j;
                float4 c0 = *(const float4*)&wp1c[d][0];
                float4 c1v = *(const float4*)&wp1c[d + 1][0];
                float4 c2 = *(const float4*)&wp1c[d + 2][0];
                float4 c3 = *(const float4*)&wp1c[d + 3][0];
                float h0 = fmaxf(px * c0.x + py * c0.y + pz * c0.z + c0.w, 0.f);
                float h1 = fmaxf(px * c1v.x + py * c1v.y + pz * c1v.z + c1v.w, 0.f);
                float h2 = fmaxf(px * c2.x + py * c2.y + pz * c2.z + c2.w, 0.f);
                float h3 = fmaxf(px * c3.x + py * c3.y + pz * c3.z + c3.w, 0.f);
                uint2 u;
                u.x = f2bf(h0) | ((unsigned int)f2bf(h1) << 16);
                u.y = f2bf(h2) | ((unsigned int)f2bf(h3) << 16);
                hp[j] = u;
            }
        }
        __syncthreads();
        // (b) Hw[p][g][d] = sum_k wt[k]*H[p*16+k][d], thread = (p,g)
        {
            float hw[DE_CH] = {};
            #pragma unroll
            for (int k = 0; k < KNN; ++k) {
                float w = wt_reg[k];
                const uint2* hp = (const uint2*)&Hs[rb + k][0];
                #pragma unroll
                for (int j = 0; j < 8; ++j) {
                    uint2 u = hp[j];
                    hw[4 * j + 0] += w * bf2f(u.x);
                    hw[4 * j + 1] += w * bf2f(u.x >> 16);
                    hw[4 * j + 2] += w * bf2f(u.y);
                    hw[4 * j + 3] += w * bf2f(u.y >> 16);
                }
            }
            uint2* op = (uint2*)&Hws[t][0];
            #pragma unroll
            for (int j = 0; j < 8; ++j) {
                uint2 u;
                u.x = f2bf(hw[4 * j + 0]) | ((unsigned int)f2bf(hw[4 * j + 1]) << 16);
                u.y = f2bf(hw[4 * j + 2]) | ((unsigned int)f2bf(hw[4 * j + 3]) << 16);
                op[j] = u;
            }
        }
        __syncthreads();
        // (c) acc[pp] += sum_d Hw[pv][gc][d] * Wp2[d][c], thread = (c,ph); 16 points each
        {
            float wcol[DE_CH];
            #pragma unroll
            for (int dr = 0; dr < DE_CH; ++dr) wcol[dr] = Wp2[(d0 + dr) * C + c];
            #pragma unroll
            for (int pp = 0; pp < 16; ++pp) {
                int rw = ((ph << 4) + pp) * 16 + gc;
                const uint2* hp = (const uint2*)&Hws[rw][0];
                float a = acc[pp];
                #pragma unroll
                for (int j = 0; j < 8; ++j) {
                    uint2 u = hp[j];
                    a += bf2f(u.x) * wcol[4 * j + 0];
                    a += bf2f(u.x >> 16) * wcol[4 * j + 1];
                    a += bf2f(u.y) * wcol[4 * j + 2];
                    a += bf2f(u.y >> 16) * wcol[4 * j + 3];
                }
                acc[pp] = a;
            }
        }
    }

    // ---- phase V: v-gather + bp2 term, thread = (c,ph); 16 points each
    #pragma unroll
    for (int pp = 0; pp < 16; ++pp) {
        int pv = (ph << 4) + pp;
        float a = acc[pp], wsum = 0.f;
        #pragma unroll
        for (int k = 0; k < KNN; ++k) {
            int r = pv * 16 + k;
            float w = w2s[r][gc];
            a += w * bf2f(vb[safe_s[r] * C + c]);
            wsum += w;
        }
        out[(n0 + pv) * C + c] = a + wsum * bp2c;
    }
}

extern "C" void kernel_launch(void* const* d_in, const int* in_sizes, int n_in,
                              void* d_out, int out_size, void* d_ws, size_t ws_size,
                              hipStream_t stream) {
    const float* feat  = (const float*)d_in[0];
    const float* coord = (const float*)d_in[1];
    const int*   knn   = (const int*)d_in[2];
    const float* Wq  = (const float*)d_in[3];
    const float* bq  = (const float*)d_in[4];
    const float* bnq = (const float*)d_in[5];
    const float* Wk  = (const float*)d_in[6];
    const float* bk  = (const float*)d_in[7];
    const float* bnk = (const float*)d_in[8];
    const float* Wv  = (const float*)d_in[9];
    const float* bv  = (const float*)d_in[10];
    const float* Wp1 = (const float*)d_in[11];
    const float* bp1 = (const float*)d_in[12];
    const float* bnp = (const float*)d_in[13];
    const float* Wp2 = (const float*)d_in[14];
    const float* bp2 = (const float*)d_in[15];
    const float* Ww1 = (const float*)d_in[16];
    const float* bw1 = (const float*)d_in[17];
    const float* bnw = (const float*)d_in[18];
    const float* Ww2 = (const float*)d_in[19];
    const float* bw2 = (const float*)d_in[20];

    float* ws    = (float*)d_ws;
    float* q_ws  = ws;
    float* k_ws  = ws + 5120000;
    unsigned short* v_ws = (unsigned short*)(ws + 10240000);
    float* qw1   = ws + 15360000;
    float* kw1   = ws + 15760000;
    float* w2w1  = ws + 16160000;
    float* c1    = ws + 16164096;
    float* outp  = (float*)d_out;

    hipLaunchKernelGGL(k_prep, dim3(257), dim3(256), 0, stream,
                       Wp2, bp2, Ww1, bw1, w2w1, c1);
    hipLaunchKernelGGL(k_qkv, dim3(157, 2, 3), dim3(256), 0, stream,
                       feat, Wq, bq, bnq, Wk, bk, bnk, Wv, bv, q_ws, k_ws, v_ws);
    hipLaunchKernelGGL(k_qkw, dim3(1250, 2), dim3(256), 0, stream,
                       q_ws, k_ws, Ww1, qw1, kw1);
    hipLaunchKernelGGL(k_attn, dim3(625), dim3(512), 0, stream,
                       coord, knn, Wp1, bp1, bnp, Wp2, bp2, Ww2, bw2, bnw,
                       w2w1, c1, qw1, kw1, v_ws, outp);
}

// Round 4
// 393.215 us; speedup vs baseline: 1.7641x; 1.1920x over previous
//
#include <hip/hip_runtime.h>
#include <hip/hip_bf16.h>

#define N_PTS 20000
#define KNN 16
#define C 256
#define G 16
#define EPS 1e-5f
#define NP 32

typedef __attribute__((ext_vector_type(8))) short short8;
typedef __attribute__((ext_vector_type(4))) float f32x4;

__device__ inline unsigned short f2bf(float f) {
    unsigned int x = __float_as_uint(f);
    unsigned int r = (x + 0x7fffu + ((x >> 16) & 1u)) >> 16;
    return (unsigned short)r;
}
__device__ inline float bf2f(unsigned int u) {
    return __uint_as_float((u & 0xffffu) << 16);
}
__device__ inline short f2bfs(float f) { return (short)f2bf(f); }

// ---------------- K0: w2w1[d][g] = Wp2@Ww1; c1 = bp2@Ww1 + bw1; Wp2bfT[c][d] = bf16(Wp2[d][c])
__global__ __launch_bounds__(256) void k_prep(const float* Wp2, const float* bp2,
                                              const float* Ww1, const float* bw1,
                                              float* w2w1, float* c1,
                                              unsigned short* wp2bft) {
    __shared__ float red[256][17];
    int t = threadIdx.x, b = blockIdx.x;
    float src = (b < C) ? Wp2[b * C + t] : bp2[t];
    #pragma unroll
    for (int g = 0; g < G; ++g) red[t][g] = src * Ww1[t * G + g];
    __syncthreads();
    for (int s = 128; s > 0; s >>= 1) {
        if (t < s) {
            #pragma unroll
            for (int g = 0; g < G; ++g) red[t][g] += red[t + s][g];
        }
        __syncthreads();
    }
    if (t < G) {
        if (b < C) w2w1[b * G + t] = red[0][t];
        else       c1[t] = red[0][t] + bw1[t];
    }
    if (b < C) wp2bft[t * C + b] = f2bf(Wp2[b * C + t]);
}

// ---------------- K1: q/k/v = feat @ W (+bias, +BN+ReLU for q,k; v -> bf16)  [unchanged]
#define BM 128
#define BN 128
#define BK 16
__global__ __launch_bounds__(256) void k_qkv(
    const float* feat, const float* Wq, const float* bq, const float* bnq,
    const float* Wk, const float* bk, const float* bnk,
    const float* Wv, const float* bv,
    float* q_out, float* k_out, unsigned short* v_out) {
    __shared__ float As[BK][BM + 4];
    __shared__ float Bs[BK][BN + 4];
    int t = threadIdx.x;
    int m0 = blockIdx.x * BM;
    int n0 = blockIdx.y * BN;
    int z = blockIdx.z;
    const float* W    = (z == 0) ? Wq : (z == 1) ? Wk : Wv;
    const float* bias = (z == 0) ? bq : (z == 1) ? bk : bv;
    const float* bn   = (z == 0) ? bnq : bnk;

    int tx = t & 15, ty = t >> 4;
    float acc[8][8] = {};
    int arow = t >> 2, ac4 = (t & 3) * 4;
    int brow = t >> 5, bc = (t & 31) * 4;

    for (int kb = 0; kb < C; kb += BK) {
        #pragma unroll
        for (int p = 0; p < 2; ++p) {
            int r = arow + p * 64;
            int gr = m0 + r; if (gr > N_PTS - 1) gr = N_PTS - 1;
            float4 f = *(const float4*)&feat[gr * C + kb + ac4];
            As[ac4 + 0][r] = f.x; As[ac4 + 1][r] = f.y;
            As[ac4 + 2][r] = f.z; As[ac4 + 3][r] = f.w;
        }
        #pragma unroll
        for (int p = 0; p < 2; ++p) {
            int kr = brow + p * 8;
            *(float4*)&Bs[kr][bc] = *(const float4*)&W[(kb + kr) * C + n0 + bc];
        }
        __syncthreads();
        #pragma unroll
        for (int kk = 0; kk < BK; ++kk) {
            float4 a0 = *(float4*)&As[kk][ty * 8];
            float4 a1 = *(float4*)&As[kk][ty * 8 + 4];
            float4 b0 = *(float4*)&Bs[kk][tx * 8];
            float4 b1 = *(float4*)&Bs[kk][tx * 8 + 4];
            float av[8] = {a0.x, a0.y, a0.z, a0.w, a1.x, a1.y, a1.z, a1.w};
            float bw[8] = {b0.x, b0.y, b0.z, b0.w, b1.x, b1.y, b1.z, b1.w};
            #pragma unroll
            for (int i = 0; i < 8; ++i) {
                #pragma unroll
                for (int j = 0; j < 8; ++j) acc[i][j] += av[i] * bw[j];
            }
        }
        __syncthreads();
    }
    int cbase = n0 + tx * 8;
    float sc[8], sh[8];
    #pragma unroll
    for (int j = 0; j < 8; ++j) {
        int c = cbase + j;
        float bi = bias[c];
        if (z < 2) {
            float ga = bn[c], be = bn[C + c], mu = bn[2 * C + c], va = bn[3 * C + c];
            float s = ga * rsqrtf(va + EPS);
            sc[j] = s; sh[j] = (bi - mu) * s + be;
        } else { sc[j] = 1.f; sh[j] = bi; }
    }
    #pragma unroll
    for (int i = 0; i < 8; ++i) {
        int m = m0 + ty * 8 + i;
        if (m >= N_PTS) continue;
        float o[8];
        #pragma unroll
        for (int j = 0; j < 8; ++j) {
            float x = acc[i][j] * sc[j] + sh[j];
            o[j] = (z < 2) ? fmaxf(x, 0.f) : x;
        }
        if (z < 2) {
            float* dst = (z == 0) ? q_out : k_out;
            *(float4*)&dst[m * C + cbase]     = make_float4(o[0], o[1], o[2], o[3]);
            *(float4*)&dst[m * C + cbase + 4] = make_float4(o[4], o[5], o[6], o[7]);
        } else {
            unsigned int p0 = f2bf(o[0]) | ((unsigned int)f2bf(o[1]) << 16);
            unsigned int p1 = f2bf(o[2]) | ((unsigned int)f2bf(o[3]) << 16);
            unsigned int p2 = f2bf(o[4]) | ((unsigned int)f2bf(o[5]) << 16);
            unsigned int p3 = f2bf(o[6]) | ((unsigned int)f2bf(o[7]) << 16);
            *(uint4*)&v_out[m * C + cbase] = make_uint4(p0, p1, p2, p3);
        }
    }
}

// ---------------- K2: qw1 = q @ Ww1, kw1 = k @ Ww1  [unchanged]
__global__ __launch_bounds__(256) void k_qkw(const float* q_ws, const float* k_ws,
                                             const float* Ww1, float* qw1, float* kw1) {
    __shared__ float tile[16][260];
    __shared__ float wT[G][260];
    int t = threadIdx.x;
    const float* src = blockIdx.y ? k_ws : q_ws;
    float* dst = blockIdx.y ? kw1 : qw1;
    int r0 = blockIdx.x * 16;
    #pragma unroll
    for (int i = 0; i < 16; ++i) {
        int e = t + 256 * i;
        wT[e & 15][e >> 4] = Ww1[e];
    }
    #pragma unroll
    for (int i = 0; i < 4; ++i) {
        int e4 = t + 256 * i;
        int row = e4 >> 6, col = (e4 & 63) * 4;
        *(float4*)&tile[row][col] = *(const float4*)&src[(r0 + row) * C + col];
    }
    __syncthreads();
    int r = t >> 4, g = t & 15;
    float acc = 0.f;
    for (int c = 0; c < C; c += 4) {
        float4 a = *(float4*)&tile[r][c];
        float4 w = *(float4*)&wT[g][c];
        acc += a.x * w.x + a.y * w.y + a.z * w.z + a.w * w.w;
    }
    dst[(r0 + r) * G + g] = acc;
}

// ---------------- K3: fused MFMA attention, 32 points / 512 threads / 8 waves
__global__ __launch_bounds__(512, 4) void k_attn(
    const float* __restrict__ coord, const int* __restrict__ knn,
    const float* __restrict__ Wp1, const float* __restrict__ bp1, const float* __restrict__ bnp,
    const float* __restrict__ bp2,
    const float* __restrict__ Ww2, const float* __restrict__ bw2, const float* __restrict__ bnw,
    const float* __restrict__ w2w1, const float* __restrict__ c1,
    const float* __restrict__ qw1, const float* __restrict__ kw1,
    const unsigned short* __restrict__ vb, const unsigned short* __restrict__ wp2bft,
    float* __restrict__ out)
{
    __shared__ __align__(16) float posm[512][4];              // 8 KB (pre-masked pos, mask)
    __shared__ __align__(16) int   safe_s[512];               // 2 KB
    __shared__ __align__(16) float wp1c[256][4];              // 4 KB (w*s, sh)
    __shared__ __align__(16) unsigned short w2w1T[16][264];   // 8.25 KB bf16 [g][d]
    __shared__ __align__(16) float Ww2s[16][16];              // 1 KB
    __shared__ __align__(16) unsigned short wt_l[32][16][24]; // 24 KB bf16 [p][g][k], k=16 -> wsum
    __shared__ __align__(16) unsigned short HT[16][520];      // 16.25 KB bf16 [d_local][row]
    __shared__ __align__(16) unsigned short Hw2[16][32][16];  // 16 KB bf16 [g][p][d_local]

    const int t = threadIdx.x;
    const int n0 = blockIdx.x * NP;
    const int wv = t >> 6, lane = t & 63, h = lane >> 4, ln = lane & 15;

    // per-lane (g = ln) BN-w / bias constants
    float scwv, shwv, bw2v, c1v;
    {
        float ga = bnw[ln], be = bnw[G + ln], mu = bnw[2 * G + ln], va = bnw[3 * G + ln];
        scwv = ga * rsqrtf(va + EPS);
        shwv = be - mu * scwv;
        bw2v = bw2[ln];
        c1v  = c1[ln];
    }

    // ---- stage
    #pragma unroll
    for (int i = 0; i < 8; ++i) {
        int e = t + 512 * i;                  // 4096 = 256 d x 16 g
        w2w1T[e & 15][e >> 4] = f2bf(w2w1[e]);
    }
    if (t < C) {
        float ga = bnp[t], be = bnp[C + t], mu = bnp[2 * C + t], va = bnp[3 * C + t];
        float s = ga * rsqrtf(va + EPS);
        wp1c[t][0] = Wp1[t] * s;
        wp1c[t][1] = Wp1[C + t] * s;
        wp1c[t][2] = Wp1[2 * C + t] * s;
        wp1c[t][3] = (bp1[t] - mu) * s + be;
    } else {
        int i = t - 256;
        Ww2s[i >> 4][i & 15] = Ww2[i];
    }
    {   // pos/mask/safe, thread = row
        const int n = n0 + (t >> 4);
        int ii = knn[n * KNN + (t & 15)];
        float mk = (ii >= 0) ? 1.f : 0.f;
        int safe = ii < 0 ? 0 : ii;
        safe_s[t] = safe;
        posm[t][0] = (coord[safe * 3]     - coord[n * 3])     * mk;
        posm[t][1] = (coord[safe * 3 + 1] - coord[n * 3 + 1]) * mk;
        posm[t][2] = (coord[safe * 3 + 2] - coord[n * 3 + 2]) * mk;
        posm[t][3] = mk;
    }
    __syncthreads();

    // ---- per-wave row-tile pos preload: wave wv owns rows 64wv..64wv+63 (points 4wv..4wv+3)
    float prx[4], pry[4], prz[4];
    #pragma unroll
    for (int q = 0; q < 4; ++q) {
        int r = 64 * wv + 16 * q + ln;
        float4 pm = *(const float4*)&posm[r][0];
        prx[q] = pm.x; pry[q] = pm.y; prz[q] = pm.z;
    }

    // ---- phase B: w1acc[row][g] = H @ w2w1  (MFMA, A computed in-flight)
    f32x4 accB[4];
    #pragma unroll
    for (int q = 0; q < 4; ++q) accB[q] = (f32x4){0.f, 0.f, 0.f, 0.f};
    for (int ks = 0; ks < 8; ++ks) {
        int d0 = ks * 32 + h * 8;
        float4 wpc[8];
        #pragma unroll
        for (int j = 0; j < 8; ++j) wpc[j] = *(const float4*)&wp1c[d0 + j][0];
        short8 bfr = *(const short8*)&w2w1T[ln][d0];
        #pragma unroll
        for (int q = 0; q < 4; ++q) {
            short8 afr;
            #pragma unroll
            for (int j = 0; j < 8; ++j) {
                float hh = fmaxf(prx[q] * wpc[j].x + pry[q] * wpc[j].y + prz[q] * wpc[j].z + wpc[j].w, 0.f);
                afr[j] = f2bfs(hh);
            }
            accB[q] = __builtin_amdgcn_mfma_f32_16x16x32_bf16(afr, bfr, accB[q], 0, 0, 0);
        }
    }

    // ---- epilogue(BN+ReLU+offs) + phase C (in-wave shuffles) + softmax + wt store
    #pragma unroll
    for (int q = 0; q < 4; ++q) {
        const int p = 4 * wv + q;
        float w1r[4], w2r[4];
        #pragma unroll
        for (int reg = 0; reg < 4; ++reg) {
            int rowg = 64 * wv + 16 * q + 4 * h + reg;
            float mk = posm[rowg][3];
            int safe = safe_s[rowg];
            float kv = kw1[safe * G + ln];
            float qv = qw1[(n0 + p) * G + ln];
            float x = accB[q][reg] + kv * mk - qv + c1v;
            w1r[reg] = fmaxf(scwv * x + shwv, 0.f);
            w2r[reg] = bw2v;
        }
        #pragma unroll
        for (int g = 0; g < 16; ++g) {
            float wvv = Ww2s[g][ln];
            int src = (lane & 48) | g;
            #pragma unroll
            for (int reg = 0; reg < 4; ++reg)
                w2r[reg] += __shfl(w1r[reg], src, 64) * wvv;
        }
        // softmax over k = 4h+reg
        float m = fmaxf(fmaxf(w2r[0], w2r[1]), fmaxf(w2r[2], w2r[3]));
        m = fmaxf(m, __shfl_xor(m, 16, 64));
        m = fmaxf(m, __shfl_xor(m, 32, 64));
        float e[4], s = 0.f;
        #pragma unroll
        for (int reg = 0; reg < 4; ++reg) { e[reg] = __expf(w2r[reg] - m); s += e[reg]; }
        s += __shfl_xor(s, 16, 64);
        s += __shfl_xor(s, 32, 64);
        float inv = 1.f / s;
        float ws4 = 0.f;
        #pragma unroll
        for (int reg = 0; reg < 4; ++reg) {
            int rowg = 64 * wv + 16 * q + 4 * h + reg;
            float wt = e[reg] * inv * posm[rowg][3];
            ws4 += wt;
            wt_l[p][ln][4 * h + reg] = f2bf(wt);
        }
        ws4 += __shfl_xor(ws4, 16, 64);
        ws4 += __shfl_xor(ws4, 32, 64);
        if (h == 0) wt_l[p][ln][16] = f2bf(ws4);
    }

    // ---- chunk loop: (a) H->HT ; (c)(ch-1) ; bar ; (b) wt x HT -> Hw2 ; bar
    float px0 = posm[t][0], py0 = posm[t][1], pz0 = posm[t][2];
    const int gq = 4 * (wv >> 1);
    const int m2 = wv & 1;
    f32x4 cacc[4];
    #pragma unroll
    for (int qq = 0; qq < 4; ++qq) cacc[qq] = (f32x4){0.f, 0.f, 0.f, 0.f};
    const short8 z8 = (short8){0, 0, 0, 0, 0, 0, 0, 0};

    for (int ch = 0; ch < 16; ++ch) {
        // (a): H chunk -> HT, thread = row
        #pragma unroll
        for (int dl = 0; dl < 16; ++dl) {
            float4 cc = *(const float4*)&wp1c[ch * 16 + dl][0];
            float hh = fmaxf(px0 * cc.x + py0 * cc.y + pz0 * cc.z + cc.w, 0.f);
            HT[dl][t] = f2bf(hh);
        }
        // (c) for previous chunk
        if (ch > 0) {
            int dc = (ch - 1) * 16;
            #pragma unroll
            for (int qq = 0; qq < 4; ++qq) {
                int g = gq + qq;
                short8 a = z8, b = z8;
                if (h < 2) {
                    a = *(const short8*)&Hw2[g][16 * m2 + ln][8 * h];
                    b = *(const short8*)&wp2bft[(16 * g + ln) * C + dc + 8 * h];
                }
                cacc[qq] = __builtin_amdgcn_mfma_f32_16x16x32_bf16(a, b, cacc[qq], 0, 0, 0);
            }
        }
        __syncthreads();
        // (b): Hw[g][d] = sum_k wt[g][k] * H[p*16+k][d]  (K=16 zero-padded to 32)
        #pragma unroll
        for (int q = 0; q < 4; ++q) {
            int p = 4 * wv + q;
            short8 a = z8, b = z8;
            if (h < 2) {
                a = *(const short8*)&wt_l[p][ln][8 * h];
                b = *(const short8*)&HT[ln][p * 16 + 8 * h];
            }
            f32x4 hw = __builtin_amdgcn_mfma_f32_16x16x32_bf16(a, b, (f32x4){0.f, 0.f, 0.f, 0.f}, 0, 0, 0);
            #pragma unroll
            for (int reg = 0; reg < 4; ++reg)
                Hw2[4 * h + reg][p][ln] = f2bf(hw[reg]);
        }
        __syncthreads();
    }
    {   // final (c), ch = 15
        int dc = 15 * 16;
        #pragma unroll
        for (int qq = 0; qq < 4; ++qq) {
            int g = gq + qq;
            short8 a = z8, b = z8;
            if (h < 2) {
                a = *(const short8*)&Hw2[g][16 * m2 + ln][8 * h];
                b = *(const short8*)&wp2bft[(16 * g + ln) * C + dc + 8 * h];
            }
            cacc[qq] = __builtin_amdgcn_mfma_f32_16x16x32_bf16(a, b, cacc[qq], 0, 0, 0);
        }
    }

    // ---- epilogue: out = peb_acc + sum_k wt*v + wsum*bp2
    #pragma unroll
    for (int qq = 0; qq < 4; ++qq) {
        int g = gq + qq;
        int c = 16 * g + ln;
        float bp2v = bp2[c];
        #pragma unroll
        for (int reg = 0; reg < 4; ++reg) {
            int p = 16 * m2 + 4 * h + reg;
            int rb = p * 16;
            float wsumv = bf2f(wt_l[p][g][16]);
            float vs = 0.f;
            #pragma unroll
            for (int k = 0; k < KNN; ++k) {
                float wvv = bf2f(wt_l[p][g][k]);
                int sf = safe_s[rb + k];
                vs += wvv * bf2f(vb[sf * C + c]);
            }
            out[(n0 + p) * C + c] = cacc[qq][reg] + vs + wsumv * bp2v;
        }
    }
}

extern "C" void kernel_launch(void* const* d_in, const int* in_sizes, int n_in,
                              void* d_out, int out_size, void* d_ws, size_t ws_size,
                              hipStream_t stream) {
    const float* feat  = (const float*)d_in[0];
    const float* coord = (const float*)d_in[1];
    const int*   knn   = (const int*)d_in[2];
    const float* Wq  = (const float*)d_in[3];
    const float* bq  = (const float*)d_in[4];
    const float* bnq = (const float*)d_in[5];
    const float* Wk  = (const float*)d_in[6];
    const float* bk  = (const float*)d_in[7];
    const float* bnk = (const float*)d_in[8];
    const float* Wv  = (const float*)d_in[9];
    const float* bv  = (const float*)d_in[10];
    const float* Wp1 = (const float*)d_in[11];
    const float* bp1 = (const float*)d_in[12];
    const float* bnp = (const float*)d_in[13];
    const float* Wp2 = (const float*)d_in[14];
    const float* bp2 = (const float*)d_in[15];
    const float* Ww1 = (const float*)d_in[16];
    const float* bw1 = (const float*)d_in[17];
    const float* bnw = (const float*)d_in[18];
    const float* Ww2 = (const float*)d_in[19];
    const float* bw2 = (const float*)d_in[20];

    float* ws    = (float*)d_ws;
    float* q_ws  = ws;
    float* k_ws  = ws + 5120000;
    unsigned short* v_ws = (unsigned short*)(ws + 10240000);
    float* qw1   = ws + 15360000;
    float* kw1   = ws + 15760000;
    float* w2w1  = ws + 16160000;
    float* c1    = ws + 16164096;
    unsigned short* wp2bft = (unsigned short*)(ws + 16200000);
    float* outp  = (float*)d_out;

    hipLaunchKernelGGL(k_prep, dim3(257), dim3(256), 0, stream,
                       Wp2, bp2, Ww1, bw1, w2w1, c1, wp2bft);
    hipLaunchKernelGGL(k_qkv, dim3(157, 2, 3), dim3(256), 0, stream,
                       feat, Wq, bq, bnq, Wk, bk, bnk, Wv, bv, q_ws, k_ws, v_ws);
    hipLaunchKernelGGL(k_qkw, dim3(1250, 2), dim3(256), 0, stream,
                       q_ws, k_ws, Ww1, qw1, kw1);
    hipLaunchKernelGGL(k_attn, dim3(625), dim3(512), 0, stream,
                       coord, knn, Wp1, bp1, bnp, bp2, Ww2, bw2, bnw,
                       w2w1, c1, qw1, kw1, v_ws, wp2bft, outp);
}

// Round 5
// 328.768 us; speedup vs baseline: 2.1099x; 1.1960x over previous
//
#include <hip/hip_runtime.h>
#include <hip/hip_bf16.h>

#define N_PTS 20000
#define KNN 16
#define C 256
#define G 16
#define EPS 1e-5f
#define NP 32

typedef __attribute__((ext_vector_type(8))) short short8;
typedef __attribute__((ext_vector_type(4))) float f32x4;

__device__ inline unsigned short f2bf(float f) {
    unsigned int x = __float_as_uint(f);
    unsigned int r = (x + 0x7fffu + ((x >> 16) & 1u)) >> 16;
    return (unsigned short)r;
}
__device__ inline float bf2f(unsigned int u) {
    return __uint_as_float((u & 0xffffu) << 16);
}
__device__ inline short f2bfs(float f) { return (short)f2bf(f); }

// ---------------- K0: w2w1[d][g] = Wp2@Ww1; c1 = bp2@Ww1 + bw1; Wp2bfT[c][d] = bf16(Wp2[d][c])
__global__ __launch_bounds__(256) void k_prep(const float* Wp2, const float* bp2,
                                              const float* Ww1, const float* bw1,
                                              float* w2w1, float* c1,
                                              unsigned short* wp2bft) {
    __shared__ float red[256][17];
    int t = threadIdx.x, b = blockIdx.x;
    float src = (b < C) ? Wp2[b * C + t] : bp2[t];
    #pragma unroll
    for (int g = 0; g < G; ++g) red[t][g] = src * Ww1[t * G + g];
    __syncthreads();
    for (int s = 128; s > 0; s >>= 1) {
        if (t < s) {
            #pragma unroll
            for (int g = 0; g < G; ++g) red[t][g] += red[t + s][g];
        }
        __syncthreads();
    }
    if (t < G) {
        if (b < C) w2w1[b * G + t] = red[0][t];
        else       c1[t] = red[0][t] + bw1[t];
    }
    if (b < C) wp2bft[t * C + b] = f2bf(Wp2[b * C + t]);
}

// ---------------- K1: q/k/v = feat @ W via bf16 MFMA (+bias, +BN+ReLU for q,k); all outputs bf16
// BM=128 rows, BN=256 (full width), BK=32. 512 thr = 8 waves (2 M x 4 N), wave tile 64x64.
__global__ __launch_bounds__(512, 2) void k_qkv(
    const float* __restrict__ feat,
    const float* __restrict__ Wq, const float* __restrict__ bq, const float* __restrict__ bnq,
    const float* __restrict__ Wk, const float* __restrict__ bk, const float* __restrict__ bnk,
    const float* __restrict__ Wv, const float* __restrict__ bv,
    unsigned short* __restrict__ q_out, unsigned short* __restrict__ k_out,
    unsigned short* __restrict__ v_out) {
    __shared__ __align__(16) unsigned short Asl[128][40];   // [m][k] bf16, pad 8
    __shared__ __align__(16) unsigned short Bsl[256][40];   // [n][k] bf16, pad 8

    const int t = threadIdx.x;
    const int m0 = blockIdx.x * 128;
    const int z = blockIdx.z;
    const float* W    = (z == 0) ? Wq : (z == 1) ? Wk : Wv;
    const float* bias = (z == 0) ? bq : (z == 1) ? bk : bv;
    const float* bn   = (z == 0) ? bnq : bnk;

    const int wv = t >> 6, lane = t & 63, h = lane >> 4, ln = lane & 15;
    const int wm = wv >> 2, wn = wv & 3;

    f32x4 acc[4][4];
    #pragma unroll
    for (int i = 0; i < 4; ++i)
        #pragma unroll
        for (int j = 0; j < 4; ++j) acc[i][j] = (f32x4){0.f, 0.f, 0.f, 0.f};

    const int ar = t >> 3, ak = (t & 7) * 4;       // A staging: 64 rows/pass, 2 passes
    const int bk_n = (t & 63) * 4, bk_k = t >> 6;  // B staging: 8 k/pass, 4 passes

    for (int kb = 0; kb < C; kb += 32) {
        #pragma unroll
        for (int ps = 0; ps < 2; ++ps) {
            int r = ar + 64 * ps;
            int gm = m0 + r; if (gm > N_PTS - 1) gm = N_PTS - 1;
            float4 f = *(const float4*)&feat[gm * C + kb + ak];
            unsigned int u0 = f2bf(f.x) | ((unsigned int)f2bf(f.y) << 16);
            unsigned int u1 = f2bf(f.z) | ((unsigned int)f2bf(f.w) << 16);
            *(uint2*)&Asl[r][ak] = make_uint2(u0, u1);
        }
        #pragma unroll
        for (int ps = 0; ps < 4; ++ps) {
            int kk = bk_k + 8 * ps;
            float4 w = *(const float4*)&W[(kb + kk) * C + bk_n];
            Bsl[bk_n + 0][kk] = f2bf(w.x);
            Bsl[bk_n + 1][kk] = f2bf(w.y);
            Bsl[bk_n + 2][kk] = f2bf(w.z);
            Bsl[bk_n + 3][kk] = f2bf(w.w);
        }
        __syncthreads();
        short8 af[4], bf[4];
        #pragma unroll
        for (int mf = 0; mf < 4; ++mf) af[mf] = *(const short8*)&Asl[64 * wm + 16 * mf + ln][8 * h];
        #pragma unroll
        for (int nf = 0; nf < 4; ++nf) bf[nf] = *(const short8*)&Bsl[64 * wn + 16 * nf + ln][8 * h];
        #pragma unroll
        for (int mf = 0; mf < 4; ++mf)
            #pragma unroll
            for (int nf = 0; nf < 4; ++nf)
                acc[mf][nf] = __builtin_amdgcn_mfma_f32_16x16x32_bf16(af[mf], bf[nf], acc[mf][nf], 0, 0, 0);
        __syncthreads();
    }

    // epilogue: BN/ReLU (q,k) or bias (v); store bf16
    unsigned short* dst = (z == 0) ? q_out : (z == 1) ? k_out : v_out;
    float scv[4], shv[4];
    int cidx[4];
    #pragma unroll
    for (int nf = 0; nf < 4; ++nf) {
        int c = 64 * wn + 16 * nf + ln;
        cidx[nf] = c;
        float bi = bias[c];
        if (z < 2) {
            float ga = bn[c], be = bn[C + c], mu = bn[2 * C + c], va = bn[3 * C + c];
            float s = ga * rsqrtf(va + EPS);
            scv[nf] = s; shv[nf] = (bi - mu) * s + be;
        } else { scv[nf] = 1.f; shv[nf] = bi; }
    }
    #pragma unroll
    for (int mf = 0; mf < 4; ++mf) {
        #pragma unroll
        for (int reg = 0; reg < 4; ++reg) {
            int m = m0 + 64 * wm + 16 * mf + 4 * h + reg;
            if (m >= N_PTS) continue;
            #pragma unroll
            for (int nf = 0; nf < 4; ++nf) {
                float x = acc[mf][nf][reg] * scv[nf] + shv[nf];
                if (z < 2) x = fmaxf(x, 0.f);
                dst[m * C + cidx[nf]] = f2bf(x);
            }
        }
    }
}

// ---------------- K2: qw1 = q @ Ww1, kw1 = k @ Ww1  (bf16 inputs)
__global__ __launch_bounds__(256) void k_qkw(const unsigned short* q_ws, const unsigned short* k_ws,
                                             const float* Ww1, float* qw1, float* kw1) {
    __shared__ float tile[16][260];
    __shared__ float wT[G][260];
    int t = threadIdx.x;
    const unsigned short* src = blockIdx.y ? k_ws : q_ws;
    float* dst = blockIdx.y ? kw1 : qw1;
    int r0 = blockIdx.x * 16;
    #pragma unroll
    for (int i = 0; i < 16; ++i) {
        int e = t + 256 * i;
        wT[e & 15][e >> 4] = Ww1[e];
    }
    #pragma unroll
    for (int i = 0; i < 4; ++i) {
        int e4 = t + 256 * i;                // 1024 groups of 4 bf16
        int row = e4 >> 6, col = (e4 & 63) * 4;
        uint2 u = *(const uint2*)&src[(r0 + row) * C + col];
        tile[row][col + 0] = bf2f(u.x);
        tile[row][col + 1] = bf2f(u.x >> 16);
        tile[row][col + 2] = bf2f(u.y);
        tile[row][col + 3] = bf2f(u.y >> 16);
    }
    __syncthreads();
    int r = t >> 4, g = t & 15;
    float acc = 0.f;
    for (int c = 0; c < C; c += 4) {
        float4 a = *(float4*)&tile[r][c];
        float4 w = *(float4*)&wT[g][c];
        acc += a.x * w.x + a.y * w.y + a.z * w.z + a.w * w.w;
    }
    dst[(r0 + r) * G + g] = acc;
}

// ---------------- K3: fused MFMA attention, 32 points / 512 threads / 8 waves
__global__ __launch_bounds__(512, 2) void k_attn(
    const float* __restrict__ coord, const int* __restrict__ knn,
    const float* __restrict__ Wp1, const float* __restrict__ bp1, const float* __restrict__ bnp,
    const float* __restrict__ bp2,
    const float* __restrict__ Ww2, const float* __restrict__ bw2, const float* __restrict__ bnw,
    const float* __restrict__ w2w1, const float* __restrict__ c1,
    const float* __restrict__ qw1, const float* __restrict__ kw1,
    const unsigned short* __restrict__ vb, const unsigned short* __restrict__ wp2bft,
    float* __restrict__ out)
{
    __shared__ __align__(16) float posm[512][4];              // 8 KB (pre-masked pos, mask)
    __shared__ __align__(16) int   safe_s[512];               // 2 KB
    __shared__ __align__(16) float wp1c[256][4];              // 4 KB (w*s, sh)
    __shared__ __align__(16) unsigned short w2w1T[16][264];   // 8.25 KB bf16 [g][d]
    __shared__ __align__(16) float Ww2s[16][16];              // 1 KB
    __shared__ __align__(16) unsigned short wt_l[32][16][24]; // 24 KB bf16 [p][g][k], k=16 -> wsum
    __shared__ __align__(16) unsigned short HT[16][520];      // 16.25 KB bf16 [d_local][row]
    __shared__ __align__(16) unsigned short Hw2[16][32][16];  // 16 KB bf16 [g][p][d_local]

    const int t = threadIdx.x;
    const int n0 = blockIdx.x * NP;
    const int wv = t >> 6, lane = t & 63, h = lane >> 4, ln = lane & 15;

    // per-lane (g = ln) BN-w / bias constants
    float scwv, shwv, bw2v, c1v;
    {
        float ga = bnw[ln], be = bnw[G + ln], mu = bnw[2 * G + ln], va = bnw[3 * G + ln];
        scwv = ga * rsqrtf(va + EPS);
        shwv = be - mu * scwv;
        bw2v = bw2[ln];
        c1v  = c1[ln];
    }

    // ---- stage
    #pragma unroll
    for (int i = 0; i < 8; ++i) {
        int e = t + 512 * i;                  // 4096 = 256 d x 16 g
        w2w1T[e & 15][e >> 4] = f2bf(w2w1[e]);
    }
    if (t < C) {
        float ga = bnp[t], be = bnp[C + t], mu = bnp[2 * C + t], va = bnp[3 * C + t];
        float s = ga * rsqrtf(va + EPS);
        wp1c[t][0] = Wp1[t] * s;
        wp1c[t][1] = Wp1[C + t] * s;
        wp1c[t][2] = Wp1[2 * C + t] * s;
        wp1c[t][3] = (bp1[t] - mu) * s + be;
    } else {
        int i = t - 256;
        Ww2s[i >> 4][i & 15] = Ww2[i];
    }
    {   // pos/mask/safe, thread = row
        const int n = n0 + (t >> 4);
        int ii = knn[n * KNN + (t & 15)];
        float mk = (ii >= 0) ? 1.f : 0.f;
        int safe = ii < 0 ? 0 : ii;
        safe_s[t] = safe;
        posm[t][0] = (coord[safe * 3]     - coord[n * 3])     * mk;
        posm[t][1] = (coord[safe * 3 + 1] - coord[n * 3 + 1]) * mk;
        posm[t][2] = (coord[safe * 3 + 2] - coord[n * 3 + 2]) * mk;
        posm[t][3] = mk;
    }
    __syncthreads();

    // ---- per-wave row-tile pos preload: wave wv owns rows 64wv..64wv+63 (points 4wv..4wv+3)
    float prx[4], pry[4], prz[4];
    #pragma unroll
    for (int q = 0; q < 4; ++q) {
        int r = 64 * wv + 16 * q + ln;
        float4 pm = *(const float4*)&posm[r][0];
        prx[q] = pm.x; pry[q] = pm.y; prz[q] = pm.z;
    }

    // ---- phase B: w1acc[row][g] = H @ w2w1  (MFMA, A computed in-flight)
    f32x4 accB[4];
    #pragma unroll
    for (int q = 0; q < 4; ++q) accB[q] = (f32x4){0.f, 0.f, 0.f, 0.f};
    for (int ks = 0; ks < 8; ++ks) {
        int d0 = ks * 32 + h * 8;
        float4 wpc[8];
        #pragma unroll
        for (int j = 0; j < 8; ++j) wpc[j] = *(const float4*)&wp1c[d0 + j][0];
        short8 bfr = *(const short8*)&w2w1T[ln][d0];
        #pragma unroll
        for (int q = 0; q < 4; ++q) {
            short8 afr;
            #pragma unroll
            for (int j = 0; j < 8; ++j) {
                float hh = fmaxf(prx[q] * wpc[j].x + pry[q] * wpc[j].y + prz[q] * wpc[j].z + wpc[j].w, 0.f);
                afr[j] = f2bfs(hh);
            }
            accB[q] = __builtin_amdgcn_mfma_f32_16x16x32_bf16(afr, bfr, accB[q], 0, 0, 0);
        }
    }

    // ---- epilogue(BN+ReLU+offs) + phase C (in-wave shuffles) + softmax + wt store
    #pragma unroll
    for (int q = 0; q < 4; ++q) {
        const int p = 4 * wv + q;
        float w1r[4], w2r[4];
        #pragma unroll
        for (int reg = 0; reg < 4; ++reg) {
            int rowg = 64 * wv + 16 * q + 4 * h + reg;
            float mk = posm[rowg][3];
            int safe = safe_s[rowg];
            float kv = kw1[safe * G + ln];
            float qv = qw1[(n0 + p) * G + ln];
            float x = accB[q][reg] + kv * mk - qv + c1v;
            w1r[reg] = fmaxf(scwv * x + shwv, 0.f);
            w2r[reg] = bw2v;
        }
        #pragma unroll
        for (int g = 0; g < 16; ++g) {
            float wvv = Ww2s[g][ln];
            int src = (lane & 48) | g;
            #pragma unroll
            for (int reg = 0; reg < 4; ++reg)
                w2r[reg] += __shfl(w1r[reg], src, 64) * wvv;
        }
        // softmax over k = 4h+reg
        float m = fmaxf(fmaxf(w2r[0], w2r[1]), fmaxf(w2r[2], w2r[3]));
        m = fmaxf(m, __shfl_xor(m, 16, 64));
        m = fmaxf(m, __shfl_xor(m, 32, 64));
        float e[4], s = 0.f;
        #pragma unroll
        for (int reg = 0; reg < 4; ++reg) { e[reg] = __expf(w2r[reg] - m); s += e[reg]; }
        s += __shfl_xor(s, 16, 64);
        s += __shfl_xor(s, 32, 64);
        float inv = 1.f / s;
        float ws4 = 0.f;
        #pragma unroll
        for (int reg = 0; reg < 4; ++reg) {
            int rowg = 64 * wv + 16 * q + 4 * h + reg;
            float wt = e[reg] * inv * posm[rowg][3];
            ws4 += wt;
            wt_l[p][ln][4 * h + reg] = f2bf(wt);
        }
        ws4 += __shfl_xor(ws4, 16, 64);
        ws4 += __shfl_xor(ws4, 32, 64);
        if (h == 0) wt_l[p][ln][16] = f2bf(ws4);
    }

    // ---- chunk loop: (a) H->HT ; (c)(ch-1) ; bar ; (b) wt x HT -> Hw2 ; bar
    float px0 = posm[t][0], py0 = posm[t][1], pz0 = posm[t][2];
    const int gq = 4 * (wv >> 1);
    const int m2 = wv & 1;
    f32x4 cacc[4];
    #pragma unroll
    for (int qq = 0; qq < 4; ++qq) cacc[qq] = (f32x4){0.f, 0.f, 0.f, 0.f};
    const short8 z8 = (short8){0, 0, 0, 0, 0, 0, 0, 0};

    for (int ch = 0; ch < 16; ++ch) {
        // (a): H chunk -> HT, thread = row
        #pragma unroll
        for (int dl = 0; dl < 16; ++dl) {
            float4 cc = *(const float4*)&wp1c[ch * 16 + dl][0];
            float hh = fmaxf(px0 * cc.x + py0 * cc.y + pz0 * cc.z + cc.w, 0.f);
            HT[dl][t] = f2bf(hh);
        }
        // (c) for previous chunk
        if (ch > 0) {
            int dc = (ch - 1) * 16;
            #pragma unroll
            for (int qq = 0; qq < 4; ++qq) {
                int g = gq + qq;
                short8 a = z8, b = z8;
                if (h < 2) {
                    a = *(const short8*)&Hw2[g][16 * m2 + ln][8 * h];
                    b = *(const short8*)&wp2bft[(16 * g + ln) * C + dc + 8 * h];
                }
                cacc[qq] = __builtin_amdgcn_mfma_f32_16x16x32_bf16(a, b, cacc[qq], 0, 0, 0);
            }
        }
        __syncthreads();
        // (b): Hw[g][d] = sum_k wt[g][k] * H[p*16+k][d]  (K=16 zero-padded to 32)
        #pragma unroll
        for (int q = 0; q < 4; ++q) {
            int p = 4 * wv + q;
            short8 a = z8, b = z8;
            if (h < 2) {
                a = *(const short8*)&wt_l[p][ln][8 * h];
                b = *(const short8*)&HT[ln][p * 16 + 8 * h];
            }
            f32x4 hw = __builtin_amdgcn_mfma_f32_16x16x32_bf16(a, b, (f32x4){0.f, 0.f, 0.f, 0.f}, 0, 0, 0);
            #pragma unroll
            for (int reg = 0; reg < 4; ++reg)
                Hw2[4 * h + reg][p][ln] = f2bf(hw[reg]);
        }
        __syncthreads();
    }
    {   // final (c), ch = 15
        int dc = 15 * 16;
        #pragma unroll
        for (int qq = 0; qq < 4; ++qq) {
            int g = gq + qq;
            short8 a = z8, b = z8;
            if (h < 2) {
                a = *(const short8*)&Hw2[g][16 * m2 + ln][8 * h];
                b = *(const short8*)&wp2bft[(16 * g + ln) * C + dc + 8 * h];
            }
            cacc[qq] = __builtin_amdgcn_mfma_f32_16x16x32_bf16(a, b, cacc[qq], 0, 0, 0);
        }
    }

    // ---- epilogue: out = peb_acc + sum_k wt*v + wsum*bp2
    #pragma unroll
    for (int qq = 0; qq < 4; ++qq) {
        int g = gq + qq;
        int c = 16 * g + ln;
        float bp2v = bp2[c];
        #pragma unroll
        for (int reg = 0; reg < 4; ++reg) {
            int p = 16 * m2 + 4 * h + reg;
            int rb = p * 16;
            float wsumv = bf2f(wt_l[p][g][16]);
            float vs = 0.f;
            #pragma unroll
            for (int k = 0; k < KNN; ++k) {
                float wvv = bf2f(wt_l[p][g][k]);
                int sf = safe_s[rb + k];
                vs += wvv * bf2f(vb[sf * C + c]);
            }
            out[(n0 + p) * C + c] = cacc[qq][reg] + vs + wsumv * bp2v;
        }
    }
}

extern "C" void kernel_launch(void* const* d_in, const int* in_sizes, int n_in,
                              void* d_out, int out_size, void* d_ws, size_t ws_size,
                              hipStream_t stream) {
    const float* feat  = (const float*)d_in[0];
    const float* coord = (const float*)d_in[1];
    const int*   knn   = (const int*)d_in[2];
    const float* Wq  = (const float*)d_in[3];
    const float* bq  = (const float*)d_in[4];
    const float* bnq = (const float*)d_in[5];
    const float* Wk  = (const float*)d_in[6];
    const float* bk  = (const float*)d_in[7];
    const float* bnk = (const float*)d_in[8];
    const float* Wv  = (const float*)d_in[9];
    const float* bv  = (const float*)d_in[10];
    const float* Wp1 = (const float*)d_in[11];
    const float* bp1 = (const float*)d_in[12];
    const float* bnp = (const float*)d_in[13];
    const float* Wp2 = (const float*)d_in[14];
    const float* bp2 = (const float*)d_in[15];
    const float* Ww1 = (const float*)d_in[16];
    const float* bw1 = (const float*)d_in[17];
    const float* bnw = (const float*)d_in[18];
    const float* Ww2 = (const float*)d_in[19];
    const float* bw2 = (const float*)d_in[20];

    float* ws = (float*)d_ws;
    unsigned short* q_ws = (unsigned short*)ws;                  // 5.12M bf16
    unsigned short* k_ws = (unsigned short*)(ws + 2560000);      // 5.12M bf16
    unsigned short* v_ws = (unsigned short*)(ws + 5120000);      // 5.12M bf16
    float* qw1   = ws + 7680000;
    float* kw1   = ws + 8080000;
    float* w2w1  = ws + 8480000;
    float* c1    = ws + 8484096;
    unsigned short* wp2bft = (unsigned short*)(ws + 8500000);    // 65536 bf16
    float* outp  = (float*)d_out;

    hipLaunchKernelGGL(k_prep, dim3(257), dim3(256), 0, stream,
                       Wp2, bp2, Ww1, bw1, w2w1, c1, wp2bft);
    hipLaunchKernelGGL(k_qkv, dim3(157, 1, 3), dim3(512), 0, stream,
                       feat, Wq, bq, bnq, Wk, bk, bnk, Wv, bv, q_ws, k_ws, v_ws);
    hipLaunchKernelGGL(k_qkw, dim3(1250, 2), dim3(256), 0, stream,
                       q_ws, k_ws, Ww1, qw1, kw1);
    hipLaunchKernelGGL(k_attn, dim3(625), dim3(512), 0, stream,
                       coord, knn, Wp1, bp1, bnp, bp2, Ww2, bw2, bnw,
                       w2w1, c1, qw1, kw1, v_ws, wp2bft, outp);
}

// Round 6
// 229.324 us; speedup vs baseline: 3.0249x; 1.4336x over previous
//
#include <hip/hip_runtime.h>
#include <hip/hip_bf16.h>

#define N_PTS 20000
#define KNN 16
#define C 256
#define G 16
#define EPS 1e-5f
#define NP 32

typedef __attribute__((ext_vector_type(8))) short short8;
typedef __attribute__((ext_vector_type(4))) float f32x4;

__device__ inline unsigned short f2bf(float f) {
    unsigned int x = __float_as_uint(f);
    unsigned int r = (x + 0x7fffu + ((x >> 16) & 1u)) >> 16;
    return (unsigned short)r;
}
__device__ inline float bf2f(unsigned int u) {
    return __uint_as_float((u & 0xffffu) << 16);
}
__device__ inline short f2bfs(float f) { return (short)f2bf(f); }

// ---------------- K0: w2w1[d][g] = Wp2@Ww1; c1 = bp2@Ww1 + bw1; Wp2bfT[c][d] = bf16(Wp2[d][c])
__global__ __launch_bounds__(256) void k_prep(const float* Wp2, const float* bp2,
                                              const float* Ww1, const float* bw1,
                                              float* w2w1, float* c1,
                                              unsigned short* wp2bft) {
    __shared__ float red[256][17];
    int t = threadIdx.x, b = blockIdx.x;
    float src = (b < C) ? Wp2[b * C + t] : bp2[t];
    #pragma unroll
    for (int g = 0; g < G; ++g) red[t][g] = src * Ww1[t * G + g];
    __syncthreads();
    for (int s = 128; s > 0; s >>= 1) {
        if (t < s) {
            #pragma unroll
            for (int g = 0; g < G; ++g) red[t][g] += red[t + s][g];
        }
        __syncthreads();
    }
    if (t < G) {
        if (b < C) w2w1[b * G + t] = red[0][t];
        else       c1[t] = red[0][t] + bw1[t];
    }
    if (b < C) wp2bft[t * C + b] = f2bf(Wp2[b * C + t]);
}

// ---------------- K1: q/k/v = feat @ W via bf16 MFMA (+bias, +BN+ReLU for q,k); all outputs bf16
__global__ __launch_bounds__(512, 2) void k_qkv(
    const float* __restrict__ feat,
    const float* __restrict__ Wq, const float* __restrict__ bq, const float* __restrict__ bnq,
    const float* __restrict__ Wk, const float* __restrict__ bk, const float* __restrict__ bnk,
    const float* __restrict__ Wv, const float* __restrict__ bv,
    unsigned short* __restrict__ q_out, unsigned short* __restrict__ k_out,
    unsigned short* __restrict__ v_out) {
    __shared__ __align__(16) unsigned short Asl[128][40];   // [m][k] bf16, pad 8
    __shared__ __align__(16) unsigned short Bsl[256][40];   // [n][k] bf16, pad 8

    const int t = threadIdx.x;
    const int m0 = blockIdx.x * 128;
    const int z = blockIdx.z;
    const float* W    = (z == 0) ? Wq : (z == 1) ? Wk : Wv;
    const float* bias = (z == 0) ? bq : (z == 1) ? bk : bv;
    const float* bn   = (z == 0) ? bnq : bnk;

    const int wv = t >> 6, lane = t & 63, h = lane >> 4, ln = lane & 15;
    const int wm = wv >> 2, wn = wv & 3;

    f32x4 acc[4][4];
    #pragma unroll
    for (int i = 0; i < 4; ++i)
        #pragma unroll
        for (int j = 0; j < 4; ++j) acc[i][j] = (f32x4){0.f, 0.f, 0.f, 0.f};

    const int ar = t >> 3, ak = (t & 7) * 4;
    const int bk_n = (t & 63) * 4, bk_k = t >> 6;

    for (int kb = 0; kb < C; kb += 32) {
        #pragma unroll
        for (int ps = 0; ps < 2; ++ps) {
            int r = ar + 64 * ps;
            int gm = m0 + r; if (gm > N_PTS - 1) gm = N_PTS - 1;
            float4 f = *(const float4*)&feat[gm * C + kb + ak];
            unsigned int u0 = f2bf(f.x) | ((unsigned int)f2bf(f.y) << 16);
            unsigned int u1 = f2bf(f.z) | ((unsigned int)f2bf(f.w) << 16);
            *(uint2*)&Asl[r][ak] = make_uint2(u0, u1);
        }
        #pragma unroll
        for (int ps = 0; ps < 4; ++ps) {
            int kk = bk_k + 8 * ps;
            float4 w = *(const float4*)&W[(kb + kk) * C + bk_n];
            Bsl[bk_n + 0][kk] = f2bf(w.x);
            Bsl[bk_n + 1][kk] = f2bf(w.y);
            Bsl[bk_n + 2][kk] = f2bf(w.z);
            Bsl[bk_n + 3][kk] = f2bf(w.w);
        }
        __syncthreads();
        short8 af[4], bf[4];
        #pragma unroll
        for (int mf = 0; mf < 4; ++mf) af[mf] = *(const short8*)&Asl[64 * wm + 16 * mf + ln][8 * h];
        #pragma unroll
        for (int nf = 0; nf < 4; ++nf) bf[nf] = *(const short8*)&Bsl[64 * wn + 16 * nf + ln][8 * h];
        #pragma unroll
        for (int mf = 0; mf < 4; ++mf)
            #pragma unroll
            for (int nf = 0; nf < 4; ++nf)
                acc[mf][nf] = __builtin_amdgcn_mfma_f32_16x16x32_bf16(af[mf], bf[nf], acc[mf][nf], 0, 0, 0);
        __syncthreads();
    }

    unsigned short* dst = (z == 0) ? q_out : (z == 1) ? k_out : v_out;
    float scv[4], shv[4];
    int cidx[4];
    #pragma unroll
    for (int nf = 0; nf < 4; ++nf) {
        int c = 64 * wn + 16 * nf + ln;
        cidx[nf] = c;
        float bi = bias[c];
        if (z < 2) {
            float ga = bn[c], be = bn[C + c], mu = bn[2 * C + c], va = bn[3 * C + c];
            float s = ga * rsqrtf(va + EPS);
            scv[nf] = s; shv[nf] = (bi - mu) * s + be;
        } else { scv[nf] = 1.f; shv[nf] = bi; }
    }
    #pragma unroll
    for (int mf = 0; mf < 4; ++mf) {
        #pragma unroll
        for (int reg = 0; reg < 4; ++reg) {
            int m = m0 + 64 * wm + 16 * mf + 4 * h + reg;
            if (m >= N_PTS) continue;
            #pragma unroll
            for (int nf = 0; nf < 4; ++nf) {
                float x = acc[mf][nf][reg] * scv[nf] + shv[nf];
                if (z < 2) x = fmaxf(x, 0.f);
                dst[m * C + cidx[nf]] = f2bf(x);
            }
        }
    }
}

// ---------------- K2: qw1 = q @ Ww1, kw1 = k @ Ww1  (bf16 inputs)
__global__ __launch_bounds__(256) void k_qkw(const unsigned short* q_ws, const unsigned short* k_ws,
                                             const float* Ww1, float* qw1, float* kw1) {
    __shared__ float tile[16][260];
    __shared__ float wT[G][260];
    int t = threadIdx.x;
    const unsigned short* src = blockIdx.y ? k_ws : q_ws;
    float* dst = blockIdx.y ? kw1 : qw1;
    int r0 = blockIdx.x * 16;
    #pragma unroll
    for (int i = 0; i < 16; ++i) {
        int e = t + 256 * i;
        wT[e & 15][e >> 4] = Ww1[e];
    }
    #pragma unroll
    for (int i = 0; i < 4; ++i) {
        int e4 = t + 256 * i;
        int row = e4 >> 6, col = (e4 & 63) * 4;
        uint2 u = *(const uint2*)&src[(r0 + row) * C + col];
        tile[row][col + 0] = bf2f(u.x);
        tile[row][col + 1] = bf2f(u.x >> 16);
        tile[row][col + 2] = bf2f(u.y);
        tile[row][col + 3] = bf2f(u.y >> 16);
    }
    __syncthreads();
    int r = t >> 4, g = t & 15;
    float acc = 0.f;
    for (int c = 0; c < C; c += 4) {
        float4 a = *(float4*)&tile[r][c];
        float4 w = *(float4*)&wT[g][c];
        acc += a.x * w.x + a.y * w.y + a.z * w.z + a.w * w.w;
    }
    dst[(r0 + r) * G + g] = acc;
}

// ---------------- K3: fused MFMA attention, 32 points / 512 threads / 8 waves
__global__ __launch_bounds__(512, 2) void k_attn(
    const float* __restrict__ coord, const int* __restrict__ knn,
    const float* __restrict__ Wp1, const float* __restrict__ bp1, const float* __restrict__ bnp,
    const float* __restrict__ bp2,
    const float* __restrict__ Ww2, const float* __restrict__ bw2, const float* __restrict__ bnw,
    const float* __restrict__ w2w1, const float* __restrict__ c1,
    const float* __restrict__ qw1, const float* __restrict__ kw1,
    const unsigned short* __restrict__ vb, const unsigned short* __restrict__ wp2bft,
    float* __restrict__ out)
{
    __shared__ __align__(16) float posm[512][4];              // 8 KB
    __shared__ __align__(16) int   safe_s[512];               // 2 KB
    __shared__ __align__(16) float wp1c[256][4];              // 4 KB
    __shared__ __align__(16) unsigned short w2w1T[16][264];   // 8.25 KB bf16 [g][d]
    __shared__ __align__(16) float Ww2s[16][16];              // 1 KB
    __shared__ __align__(16) unsigned short wt_l[32][16][24]; // 24 KB bf16 [p][g][k], k=16 -> wsum
    // HT (16x520 bf16) + Hw2 (16x32x16 bf16) region; after the chunk loop it is
    // reused (overlaid) as pebs[32][256] f32. 16512 shorts = 33024 B >= 32768 B.
    __shared__ __align__(16) unsigned short hwbuf[16512];

    const int t = threadIdx.x;
    const int n0 = blockIdx.x * NP;
    const int wv = t >> 6, lane = t & 63, h = lane >> 4, ln = lane & 15;

    float scwv, shwv, bw2v, c1v;
    {
        float ga = bnw[ln], be = bnw[G + ln], mu = bnw[2 * G + ln], va = bnw[3 * G + ln];
        scwv = ga * rsqrtf(va + EPS);
        shwv = be - mu * scwv;
        bw2v = bw2[ln];
        c1v  = c1[ln];
    }

    // ---- stage
    #pragma unroll
    for (int i = 0; i < 8; ++i) {
        int e = t + 512 * i;
        w2w1T[e & 15][e >> 4] = f2bf(w2w1[e]);
    }
    if (t < C) {
        float ga = bnp[t], be = bnp[C + t], mu = bnp[2 * C + t], va = bnp[3 * C + t];
        float s = ga * rsqrtf(va + EPS);
        wp1c[t][0] = Wp1[t] * s;
        wp1c[t][1] = Wp1[C + t] * s;
        wp1c[t][2] = Wp1[2 * C + t] * s;
        wp1c[t][3] = (bp1[t] - mu) * s + be;
    } else {
        int i = t - 256;
        Ww2s[i >> 4][i & 15] = Ww2[i];
    }
    {
        const int n = n0 + (t >> 4);
        int ii = knn[n * KNN + (t & 15)];
        float mk = (ii >= 0) ? 1.f : 0.f;
        int safe = ii < 0 ? 0 : ii;
        safe_s[t] = safe;
        posm[t][0] = (coord[safe * 3]     - coord[n * 3])     * mk;
        posm[t][1] = (coord[safe * 3 + 1] - coord[n * 3 + 1]) * mk;
        posm[t][2] = (coord[safe * 3 + 2] - coord[n * 3 + 2]) * mk;
        posm[t][3] = mk;
    }
    __syncthreads();

    float prx[4], pry[4], prz[4];
    #pragma unroll
    for (int q = 0; q < 4; ++q) {
        int r = 64 * wv + 16 * q + ln;
        float4 pm = *(const float4*)&posm[r][0];
        prx[q] = pm.x; pry[q] = pm.y; prz[q] = pm.z;
    }

    // ---- phase B: w1acc = H @ w2w1 (MFMA, A in-flight)
    f32x4 accB[4];
    #pragma unroll
    for (int q = 0; q < 4; ++q) accB[q] = (f32x4){0.f, 0.f, 0.f, 0.f};
    for (int ks = 0; ks < 8; ++ks) {
        int d0 = ks * 32 + h * 8;
        float4 wpc[8];
        #pragma unroll
        for (int j = 0; j < 8; ++j) wpc[j] = *(const float4*)&wp1c[d0 + j][0];
        short8 bfr = *(const short8*)&w2w1T[ln][d0];
        #pragma unroll
        for (int q = 0; q < 4; ++q) {
            short8 afr;
            #pragma unroll
            for (int j = 0; j < 8; ++j) {
                float hh = fmaxf(prx[q] * wpc[j].x + pry[q] * wpc[j].y + prz[q] * wpc[j].z + wpc[j].w, 0.f);
                afr[j] = f2bfs(hh);
            }
            accB[q] = __builtin_amdgcn_mfma_f32_16x16x32_bf16(afr, bfr, accB[q], 0, 0, 0);
        }
    }

    // ---- BN+ReLU+offs, phase C (shuffles), softmax, wt -> LDS
    #pragma unroll
    for (int q = 0; q < 4; ++q) {
        const int p = 4 * wv + q;
        float w1r[4], w2r[4];
        #pragma unroll
        for (int reg = 0; reg < 4; ++reg) {
            int rowg = 64 * wv + 16 * q + 4 * h + reg;
            float mk = posm[rowg][3];
            int safe = safe_s[rowg];
            float kv = kw1[safe * G + ln];
            float qv = qw1[(n0 + p) * G + ln];
            float x = accB[q][reg] + kv * mk - qv + c1v;
            w1r[reg] = fmaxf(scwv * x + shwv, 0.f);
            w2r[reg] = bw2v;
        }
        #pragma unroll
        for (int g = 0; g < 16; ++g) {
            float wvv = Ww2s[g][ln];
            int src = (lane & 48) | g;
            #pragma unroll
            for (int reg = 0; reg < 4; ++reg)
                w2r[reg] += __shfl(w1r[reg], src, 64) * wvv;
        }
        float m = fmaxf(fmaxf(w2r[0], w2r[1]), fmaxf(w2r[2], w2r[3]));
        m = fmaxf(m, __shfl_xor(m, 16, 64));
        m = fmaxf(m, __shfl_xor(m, 32, 64));
        float e[4], s = 0.f;
        #pragma unroll
        for (int reg = 0; reg < 4; ++reg) { e[reg] = __expf(w2r[reg] - m); s += e[reg]; }
        s += __shfl_xor(s, 16, 64);
        s += __shfl_xor(s, 32, 64);
        float inv = 1.f / s;
        float ws4 = 0.f;
        #pragma unroll
        for (int reg = 0; reg < 4; ++reg) {
            int rowg = 64 * wv + 16 * q + 4 * h + reg;
            float wt = e[reg] * inv * posm[rowg][3];
            ws4 += wt;
            wt_l[p][ln][4 * h + reg] = f2bf(wt);
        }
        ws4 += __shfl_xor(ws4, 16, 64);
        ws4 += __shfl_xor(ws4, 32, 64);
        if (h == 0) wt_l[p][ln][16] = f2bf(ws4);
    }

    // ---- chunk loop: (a) H->HT ; (c)(ch-1) ; bar ; (b) wt x HT -> Hw2 ; bar
    float px0 = posm[t][0], py0 = posm[t][1], pz0 = posm[t][2];
    const int gq = 4 * (wv >> 1);
    const int m2 = wv & 1;
    f32x4 cacc[4];
    #pragma unroll
    for (int qq = 0; qq < 4; ++qq) cacc[qq] = (f32x4){0.f, 0.f, 0.f, 0.f};
    const short8 z8 = (short8){0, 0, 0, 0, 0, 0, 0, 0};

    for (int ch = 0; ch < 16; ++ch) {
        // (a): H chunk -> HT, thread = row
        #pragma unroll
        for (int dl = 0; dl < 16; ++dl) {
            float4 cc = *(const float4*)&wp1c[ch * 16 + dl][0];
            float hh = fmaxf(px0 * cc.x + py0 * cc.y + pz0 * cc.z + cc.w, 0.f);
            hwbuf[dl * 520 + t] = f2bf(hh);
        }
        // (c) previous chunk
        if (ch > 0) {
            int dc = (ch - 1) * 16;
            #pragma unroll
            for (int qq = 0; qq < 4; ++qq) {
                int g = gq + qq;
                short8 a = z8, b = z8;
                if (h < 2) {
                    a = *(const short8*)&hwbuf[8320 + (g * 32 + 16 * m2 + ln) * 16 + 8 * h];
                    b = *(const short8*)&wp2bft[(16 * g + ln) * C + dc + 8 * h];
                }
                cacc[qq] = __builtin_amdgcn_mfma_f32_16x16x32_bf16(a, b, cacc[qq], 0, 0, 0);
            }
        }
        __syncthreads();
        // (b): Hw[g][d] = sum_k wt[g][k] * H[p*16+k][d]  (K=16 zero-padded)
        #pragma unroll
        for (int q = 0; q < 4; ++q) {
            int p = 4 * wv + q;
            short8 a = z8, b = z8;
            if (h < 2) {
                a = *(const short8*)&wt_l[p][ln][8 * h];
                b = *(const short8*)&hwbuf[ln * 520 + p * 16 + 8 * h];
            }
            f32x4 hw = __builtin_amdgcn_mfma_f32_16x16x32_bf16(a, b, (f32x4){0.f, 0.f, 0.f, 0.f}, 0, 0, 0);
            #pragma unroll
            for (int reg = 0; reg < 4; ++reg)
                hwbuf[8320 + ((4 * h + reg) * 32 + p) * 16 + ln] = f2bf(hw[reg]);
        }
        __syncthreads();
    }
    {   // final (c), ch = 15
        int dc = 15 * 16;
        #pragma unroll
        for (int qq = 0; qq < 4; ++qq) {
            int g = gq + qq;
            short8 a = z8, b = z8;
            if (h < 2) {
                a = *(const short8*)&hwbuf[8320 + (g * 32 + 16 * m2 + ln) * 16 + 8 * h];
                b = *(const short8*)&wp2bft[(16 * g + ln) * C + dc + 8 * h];
            }
            cacc[qq] = __builtin_amdgcn_mfma_f32_16x16x32_bf16(a, b, cacc[qq], 0, 0, 0);
        }
    }

    // ---- peb -> LDS (overlay on HT/Hw2 region), then coalesced gather epilogue
    __syncthreads();   // all waves done reading Hw2
    float (*pebs)[256] = (float (*)[256])(void*)hwbuf;
    #pragma unroll
    for (int qq = 0; qq < 4; ++qq) {
        int g = gq + qq;
        #pragma unroll
        for (int reg = 0; reg < 4; ++reg) {
            int p = 16 * m2 + 4 * h + reg;
            pebs[p][16 * g + ln] = cacc[qq][reg];
        }
    }
    __syncthreads();

    {   // thread = (point p_e, group g_e) -> 16 consecutive channels
        const int p_e = t >> 4, g_e = t & 15, c0 = g_e * 16;
        float o[16];
        #pragma unroll
        for (int j = 0; j < 16; ++j) o[j] = pebs[p_e][c0 + j];
        {
            float wsumv = bf2f(wt_l[p_e][g_e][16]);
            float4 b0 = *(const float4*)&bp2[c0];
            float4 b1 = *(const float4*)&bp2[c0 + 4];
            float4 b2 = *(const float4*)&bp2[c0 + 8];
            float4 b3 = *(const float4*)&bp2[c0 + 12];
            o[0] += wsumv * b0.x; o[1] += wsumv * b0.y; o[2] += wsumv * b0.z; o[3] += wsumv * b0.w;
            o[4] += wsumv * b1.x; o[5] += wsumv * b1.y; o[6] += wsumv * b1.z; o[7] += wsumv * b1.w;
            o[8] += wsumv * b2.x; o[9] += wsumv * b2.y; o[10] += wsumv * b2.z; o[11] += wsumv * b2.w;
            o[12] += wsumv * b3.x; o[13] += wsumv * b3.y; o[14] += wsumv * b3.z; o[15] += wsumv * b3.w;
        }
        #pragma unroll
        for (int k = 0; k < KNN; ++k) {
            int sf = safe_s[p_e * 16 + k];
            float w = bf2f(wt_l[p_e][g_e][k]);
            uint4 va = *(const uint4*)&vb[sf * C + c0];
            uint4 vc = *(const uint4*)&vb[sf * C + c0 + 8];
            o[0]  += w * bf2f(va.x); o[1]  += w * bf2f(va.x >> 16);
            o[2]  += w * bf2f(va.y); o[3]  += w * bf2f(va.y >> 16);
            o[4]  += w * bf2f(va.z); o[5]  += w * bf2f(va.z >> 16);
            o[6]  += w * bf2f(va.w); o[7]  += w * bf2f(va.w >> 16);
            o[8]  += w * bf2f(vc.x); o[9]  += w * bf2f(vc.x >> 16);
            o[10] += w * bf2f(vc.y); o[11] += w * bf2f(vc.y >> 16);
            o[12] += w * bf2f(vc.z); o[13] += w * bf2f(vc.z >> 16);
            o[14] += w * bf2f(vc.w); o[15] += w * bf2f(vc.w >> 16);
        }
        float* op = &out[(n0 + p_e) * C + c0];
        *(float4*)&op[0]  = make_float4(o[0], o[1], o[2], o[3]);
        *(float4*)&op[4]  = make_float4(o[4], o[5], o[6], o[7]);
        *(float4*)&op[8]  = make_float4(o[8], o[9], o[10], o[11]);
        *(float4*)&op[12] = make_float4(o[12], o[13], o[14], o[15]);
    }
}

extern "C" void kernel_launch(void* const* d_in, const int* in_sizes, int n_in,
                              void* d_out, int out_size, void* d_ws, size_t ws_size,
                              hipStream_t stream) {
    const float* feat  = (const float*)d_in[0];
    const float* coord = (const float*)d_in[1];
    const int*   knn   = (const int*)d_in[2];
    const float* Wq  = (const float*)d_in[3];
    const float* bq  = (const float*)d_in[4];
    const float* bnq = (const float*)d_in[5];
    const float* Wk  = (const float*)d_in[6];
    const float* bk  = (const float*)d_in[7];
    const float* bnk = (const float*)d_in[8];
    const float* Wv  = (const float*)d_in[9];
    const float* bv  = (const float*)d_in[10];
    const float* Wp1 = (const float*)d_in[11];
    const float* bp1 = (const float*)d_in[12];
    const float* bnp = (const float*)d_in[13];
    const float* Wp2 = (const float*)d_in[14];
    const float* bp2 = (const float*)d_in[15];
    const float* Ww1 = (const float*)d_in[16];
    const float* bw1 = (const float*)d_in[17];
    const float* bnw = (const float*)d_in[18];
    const float* Ww2 = (const float*)d_in[19];
    const float* bw2 = (const float*)d_in[20];

    float* ws = (float*)d_ws;
    unsigned short* q_ws = (unsigned short*)ws;                  // 5.12M bf16
    unsigned short* k_ws = (unsigned short*)(ws + 2560000);      // 5.12M bf16
    unsigned short* v_ws = (unsigned short*)(ws + 5120000);      // 5.12M bf16
    float* qw1   = ws + 7680000;
    float* kw1   = ws + 8080000;
    float* w2w1  = ws + 8480000;
    float* c1    = ws + 8484096;
    unsigned short* wp2bft = (unsigned short*)(ws + 8500000);    // 65536 bf16
    float* outp  = (float*)d_out;

    hipLaunchKernelGGL(k_prep, dim3(257), dim3(256), 0, stream,
                       Wp2, bp2, Ww1, bw1, w2w1, c1, wp2bft);
    hipLaunchKernelGGL(k_qkv, dim3(157, 1, 3), dim3(512), 0, stream,
                       feat, Wq, bq, bnq, Wk, bk, bnk, Wv, bv, q_ws, k_ws, v_ws);
    hipLaunchKernelGGL(k_qkw, dim3(1250, 2), dim3(256), 0, stream,
                       q_ws, k_ws, Ww1, qw1, kw1);
    hipLaunchKernelGGL(k_attn, dim3(625), dim3(512), 0, stream,
                       coord, knn, Wp1, bp1, bnp, bp2, Ww2, bw2, bnw,
                       w2w1, c1, qw1, kw1, v_ws, wp2bft, outp);
}

// Round 7
// 210.951 us; speedup vs baseline: 3.2883x; 1.0871x over previous
//
#include <hip/hip_runtime.h>
#include <hip/hip_bf16.h>

#define N_PTS 20000
#define KNN 16
#define C 256
#define G 16
#define EPS 1e-5f
#define NP 32

typedef __attribute__((ext_vector_type(8))) short short8;
typedef __attribute__((ext_vector_type(4))) float f32x4;

__device__ inline unsigned short f2bf(float f) {
    unsigned int x = __float_as_uint(f);
    unsigned int r = (x + 0x7fffu + ((x >> 16) & 1u)) >> 16;
    return (unsigned short)r;
}
__device__ inline float bf2f(unsigned int u) {
    return __uint_as_float((u & 0xffffu) << 16);
}
__device__ inline short f2bfs(float f) { return (short)f2bf(f); }

// ---------------- K0: w2w1[d][g] = Wp2@Ww1; c1 = bp2@Ww1 + bw1; Wp2bfT[c][d] = bf16(Wp2[d][c])
__global__ __launch_bounds__(256) void k_prep(const float* Wp2, const float* bp2,
                                              const float* Ww1, const float* bw1,
                                              float* w2w1, float* c1,
                                              unsigned short* wp2bft) {
    __shared__ float red[256][17];
    int t = threadIdx.x, b = blockIdx.x;
    float src = (b < C) ? Wp2[b * C + t] : bp2[t];
    #pragma unroll
    for (int g = 0; g < G; ++g) red[t][g] = src * Ww1[t * G + g];
    __syncthreads();
    for (int s = 128; s > 0; s >>= 1) {
        if (t < s) {
            #pragma unroll
            for (int g = 0; g < G; ++g) red[t][g] += red[t + s][g];
        }
        __syncthreads();
    }
    if (t < G) {
        if (b < C) w2w1[b * G + t] = red[0][t];
        else       c1[t] = red[0][t] + bw1[t];
    }
    if (b < C) wp2bft[t * C + b] = f2bf(Wp2[b * C + t]);
}

// ---------------- K1: q/k/v = feat @ W via bf16 MFMA (+bias, +BN+ReLU for q,k); all outputs bf16
__global__ __launch_bounds__(512, 2) void k_qkv(
    const float* __restrict__ feat,
    const float* __restrict__ Wq, const float* __restrict__ bq, const float* __restrict__ bnq,
    const float* __restrict__ Wk, const float* __restrict__ bk, const float* __restrict__ bnk,
    const float* __restrict__ Wv, const float* __restrict__ bv,
    unsigned short* __restrict__ q_out, unsigned short* __restrict__ k_out,
    unsigned short* __restrict__ v_out) {
    __shared__ __align__(16) unsigned short Asl[128][40];   // [m][k] bf16, pad 8
    __shared__ __align__(16) unsigned short Bsl[256][40];   // [n][k] bf16, pad 8

    const int t = threadIdx.x;
    const int m0 = blockIdx.x * 128;
    const int z = blockIdx.z;
    const float* W    = (z == 0) ? Wq : (z == 1) ? Wk : Wv;
    const float* bias = (z == 0) ? bq : (z == 1) ? bk : bv;
    const float* bn   = (z == 0) ? bnq : bnk;

    const int wv = t >> 6, lane = t & 63, h = lane >> 4, ln = lane & 15;
    const int wm = wv >> 2, wn = wv & 3;

    f32x4 acc[4][4];
    #pragma unroll
    for (int i = 0; i < 4; ++i)
        #pragma unroll
        for (int j = 0; j < 4; ++j) acc[i][j] = (f32x4){0.f, 0.f, 0.f, 0.f};

    const int ar = t >> 3, ak = (t & 7) * 4;
    const int bk_n = (t & 63) * 4, bk_k = t >> 6;

    for (int kb = 0; kb < C; kb += 32) {
        #pragma unroll
        for (int ps = 0; ps < 2; ++ps) {
            int r = ar + 64 * ps;
            int gm = m0 + r; if (gm > N_PTS - 1) gm = N_PTS - 1;
            float4 f = *(const float4*)&feat[gm * C + kb + ak];
            unsigned int u0 = f2bf(f.x) | ((unsigned int)f2bf(f.y) << 16);
            unsigned int u1 = f2bf(f.z) | ((unsigned int)f2bf(f.w) << 16);
            *(uint2*)&Asl[r][ak] = make_uint2(u0, u1);
        }
        #pragma unroll
        for (int ps = 0; ps < 4; ++ps) {
            int kk = bk_k + 8 * ps;
            float4 w = *(const float4*)&W[(kb + kk) * C + bk_n];
            Bsl[bk_n + 0][kk] = f2bf(w.x);
            Bsl[bk_n + 1][kk] = f2bf(w.y);
            Bsl[bk_n + 2][kk] = f2bf(w.z);
            Bsl[bk_n + 3][kk] = f2bf(w.w);
        }
        __syncthreads();
        short8 af[4], bf[4];
        #pragma unroll
        for (int mf = 0; mf < 4; ++mf) af[mf] = *(const short8*)&Asl[64 * wm + 16 * mf + ln][8 * h];
        #pragma unroll
        for (int nf = 0; nf < 4; ++nf) bf[nf] = *(const short8*)&Bsl[64 * wn + 16 * nf + ln][8 * h];
        #pragma unroll
        for (int mf = 0; mf < 4; ++mf)
            #pragma unroll
            for (int nf = 0; nf < 4; ++nf)
                acc[mf][nf] = __builtin_amdgcn_mfma_f32_16x16x32_bf16(af[mf], bf[nf], acc[mf][nf], 0, 0, 0);
        __syncthreads();
    }

    unsigned short* dst = (z == 0) ? q_out : (z == 1) ? k_out : v_out;
    float scv[4], shv[4];
    int cidx[4];
    #pragma unroll
    for (int nf = 0; nf < 4; ++nf) {
        int c = 64 * wn + 16 * nf + ln;
        cidx[nf] = c;
        float bi = bias[c];
        if (z < 2) {
            float ga = bn[c], be = bn[C + c], mu = bn[2 * C + c], va = bn[3 * C + c];
            float s = ga * rsqrtf(va + EPS);
            scv[nf] = s; shv[nf] = (bi - mu) * s + be;
        } else { scv[nf] = 1.f; shv[nf] = bi; }
    }
    #pragma unroll
    for (int mf = 0; mf < 4; ++mf) {
        #pragma unroll
        for (int reg = 0; reg < 4; ++reg) {
            int m = m0 + 64 * wm + 16 * mf + 4 * h + reg;
            if (m >= N_PTS) continue;
            #pragma unroll
            for (int nf = 0; nf < 4; ++nf) {
                float x = acc[mf][nf][reg] * scv[nf] + shv[nf];
                if (z < 2) x = fmaxf(x, 0.f);
                dst[m * C + cidx[nf]] = f2bf(x);
            }
        }
    }
}

// ---------------- K2: qw1 = q @ Ww1, kw1 = k @ Ww1  (bf16 inputs)
__global__ __launch_bounds__(256) void k_qkw(const unsigned short* q_ws, const unsigned short* k_ws,
                                             const float* Ww1, float* qw1, float* kw1) {
    __shared__ float tile[16][260];
    __shared__ float wT[G][260];
    int t = threadIdx.x;
    const unsigned short* src = blockIdx.y ? k_ws : q_ws;
    float* dst = blockIdx.y ? kw1 : qw1;
    int r0 = blockIdx.x * 16;
    #pragma unroll
    for (int i = 0; i < 16; ++i) {
        int e = t + 256 * i;
        wT[e & 15][e >> 4] = Ww1[e];
    }
    #pragma unroll
    for (int i = 0; i < 4; ++i) {
        int e4 = t + 256 * i;
        int row = e4 >> 6, col = (e4 & 63) * 4;
        uint2 u = *(const uint2*)&src[(r0 + row) * C + col];
        tile[row][col + 0] = bf2f(u.x);
        tile[row][col + 1] = bf2f(u.x >> 16);
        tile[row][col + 2] = bf2f(u.y);
        tile[row][col + 3] = bf2f(u.y >> 16);
    }
    __syncthreads();
    int r = t >> 4, g = t & 15;
    float acc = 0.f;
    for (int c = 0; c < C; c += 4) {
        float4 a = *(float4*)&tile[r][c];
        float4 w = *(float4*)&wT[g][c];
        acc += a.x * w.x + a.y * w.y + a.z * w.z + a.w * w.w;
    }
    dst[(r0 + r) * G + g] = acc;
}

// ---------------- K3: fused MFMA attention, 32 points / 512 threads / 8 waves
// LDS ~63.7 KB -> 2 blocks/CU. hwbuf overlay (shorts):
//   phase B/C : w2w1T[16][264] @0 (4224) | Ww2T[16][16] @4224 (256) | w1s[8][16][24] @4480 (3072)
//   chunk loop: HT[16][520] @0 (8320)    | Hw2[16][32][16] @8320 (8192)
//   epilogue  : pebs f32[32][256] @0 (32768 B)
__global__ __launch_bounds__(512, 2) void k_attn(
    const float* __restrict__ coord, const int* __restrict__ knn,
    const float* __restrict__ Wp1, const float* __restrict__ bp1, const float* __restrict__ bnp,
    const float* __restrict__ bp2,
    const float* __restrict__ Ww2, const float* __restrict__ bw2, const float* __restrict__ bnw,
    const float* __restrict__ w2w1, const float* __restrict__ c1,
    const float* __restrict__ qw1, const float* __restrict__ kw1,
    const unsigned short* __restrict__ vb, const unsigned short* __restrict__ wp2bft,
    float* __restrict__ out)
{
    __shared__ __align__(16) int   safe_s[512];               // 2 KB
    __shared__ __align__(16) float wp1c[256][4];              // 4 KB
    __shared__ __align__(16) unsigned short wt_l[32][16][24]; // 24 KB  [p][g][k], k=16 -> wsum
    __shared__ __align__(16) unsigned short hwbuf[16512];     // 33 KB multi-use

    const int t = threadIdx.x;
    const int n0 = blockIdx.x * NP;
    const int wv = t >> 6, lane = t & 63, h = lane >> 4, ln = lane & 15;
    const short8 z8 = (short8){0, 0, 0, 0, 0, 0, 0, 0};

    float scwv, shwv, bw2v, c1v;
    {
        float ga = bnw[ln], be = bnw[G + ln], mu = bnw[2 * G + ln], va = bnw[3 * G + ln];
        scwv = ga * rsqrtf(va + EPS);
        shwv = be - mu * scwv;
        bw2v = bw2[ln];
        c1v  = c1[ln];
    }

    // ---- stage: w2w1T + Ww2T into hwbuf, wp1c
    #pragma unroll
    for (int i = 0; i < 8; ++i) {
        int e = t + 512 * i;                       // 4096 = 256 d x 16 g
        hwbuf[(e & 15) * 264 + (e >> 4)] = f2bf(w2w1[e]);
    }
    if (t < C) {
        float ga = bnp[t], be = bnp[C + t], mu = bnp[2 * C + t], va = bnp[3 * C + t];
        float s = ga * rsqrtf(va + EPS);
        wp1c[t][0] = Wp1[t] * s;
        wp1c[t][1] = Wp1[C + t] * s;
        wp1c[t][2] = Wp1[2 * C + t] * s;
        wp1c[t][3] = (bp1[t] - mu) * s + be;
    } else {
        int e = t - 256;                           // Ww2T[g'][g] = Ww2[g][g']
        hwbuf[4224 + (e & 15) * 16 + (e >> 4)] = f2bf(Ww2[e]);
    }
    // ---- per-thread pos/mask/safe (row = t)
    float px0, py0, pz0, mk0; int safe0;
    {
        const int n = n0 + (t >> 4);
        int ii = knn[n * KNN + (t & 15)];
        mk0 = (ii >= 0) ? 1.f : 0.f;
        safe0 = ii < 0 ? 0 : ii;
        safe_s[t] = safe0;
        px0 = (coord[safe0 * 3]     - coord[n * 3])     * mk0;
        py0 = (coord[safe0 * 3 + 1] - coord[n * 3 + 1]) * mk0;
        pz0 = (coord[safe0 * 3 + 2] - coord[n * 3 + 2]) * mk0;
    }
    __syncthreads();

    // ---- per-wave row pos via shfl (rows 64wv..64wv+63 are wave-private)
    float prx[4], pry[4], prz[4];
    #pragma unroll
    for (int q = 0; q < 4; ++q) {
        int src = 16 * q + ln;
        prx[q] = __shfl(px0, src, 64);
        pry[q] = __shfl(py0, src, 64);
        prz[q] = __shfl(pz0, src, 64);
    }

    // ---- phase B: w1acc = H @ w2w1 (MFMA, A in-flight)
    f32x4 accB[4];
    #pragma unroll
    for (int q = 0; q < 4; ++q) accB[q] = (f32x4){0.f, 0.f, 0.f, 0.f};
    for (int ks = 0; ks < 8; ++ks) {
        int d0 = ks * 32 + h * 8;
        float4 wpc[8];
        #pragma unroll
        for (int j = 0; j < 8; ++j) wpc[j] = *(const float4*)&wp1c[d0 + j][0];
        short8 bfr = *(const short8*)&hwbuf[ln * 264 + d0];
        #pragma unroll
        for (int q = 0; q < 4; ++q) {
            short8 afr;
            #pragma unroll
            for (int j = 0; j < 8; ++j) {
                float hh = fmaxf(prx[q] * wpc[j].x + pry[q] * wpc[j].y + prz[q] * wpc[j].z + wpc[j].w, 0.f);
                afr[j] = f2bfs(hh);
            }
            accB[q] = __builtin_amdgcn_mfma_f32_16x16x32_bf16(afr, bfr, accB[q], 0, 0, 0);
        }
    }

    // ---- phase C: BN+ReLU+offs -> w1 (bf16, wave-private LDS transpose) -> MFMA w2 -> softmax -> wt
    #pragma unroll
    for (int q = 0; q < 4; ++q) {
        const int p = 4 * wv + q;
        float mkq[4]; int sfq[4];
        #pragma unroll
        for (int reg = 0; reg < 4; ++reg) {
            int src = 16 * q + 4 * h + reg;
            mkq[reg] = __shfl(mk0, src, 64);
            sfq[reg] = __shfl(safe0, src, 64);
        }
        #pragma unroll
        for (int reg = 0; reg < 4; ++reg) {
            float kv = kw1[sfq[reg] * G + ln];
            float qv = qw1[(n0 + p) * G + ln];
            float x = accB[q][reg] + kv * mkq[reg] - qv + c1v;
            float w1 = fmaxf(scwv * x + shwv, 0.f);
            hwbuf[4480 + wv * 384 + (4 * h + reg) * 24 + ln] = f2bf(w1);  // w1s[k][g]
        }
        short8 a = z8, b = z8;
        if (h < 2) {
            a = *(const short8*)&hwbuf[4480 + wv * 384 + ln * 24 + 8 * h];  // A[k=ln][g=8h+j]
            b = *(const short8*)&hwbuf[4224 + ln * 16 + 8 * h];             // B[g'=ln][g=8h+j]
        }
        f32x4 w2v4 = __builtin_amdgcn_mfma_f32_16x16x32_bf16(
            a, b, (f32x4){bw2v, bw2v, bw2v, bw2v}, 0, 0, 0);
        float w2r[4] = {w2v4[0], w2v4[1], w2v4[2], w2v4[3]};
        // softmax over k = 4h+reg (rows), per g' = ln
        float m = fmaxf(fmaxf(w2r[0], w2r[1]), fmaxf(w2r[2], w2r[3]));
        m = fmaxf(m, __shfl_xor(m, 16, 64));
        m = fmaxf(m, __shfl_xor(m, 32, 64));
        float e4[4], s = 0.f;
        #pragma unroll
        for (int reg = 0; reg < 4; ++reg) { e4[reg] = __expf(w2r[reg] - m); s += e4[reg]; }
        s += __shfl_xor(s, 16, 64);
        s += __shfl_xor(s, 32, 64);
        float inv = 1.f / s;
        float ws4 = 0.f;
        #pragma unroll
        for (int reg = 0; reg < 4; ++reg) {
            float wt = e4[reg] * inv * mkq[reg];
            ws4 += wt;
            wt_l[p][ln][4 * h + reg] = f2bf(wt);
        }
        ws4 += __shfl_xor(ws4, 16, 64);
        ws4 += __shfl_xor(ws4, 32, 64);
        if (h == 0) wt_l[p][ln][16] = f2bf(ws4);
    }

    __syncthreads();   // phase-B/C hwbuf region dead; safe to reuse as HT/Hw2

    // ---- chunk loop: (a) H->HT ; (c)(ch-1) ; bar ; (b) wt x HT -> Hw2 ; bar
    short8 awt[4];     // loop-invariant (b) A-fragments
    #pragma unroll
    for (int q = 0; q < 4; ++q)
        awt[q] = (h < 2) ? *(const short8*)&wt_l[4 * wv + q][ln][8 * h] : z8;

    const int gq = 4 * (wv >> 1);
    const int m2 = wv & 1;
    f32x4 cacc[4];
    #pragma unroll
    for (int qq = 0; qq < 4; ++qq) cacc[qq] = (f32x4){0.f, 0.f, 0.f, 0.f};

    for (int ch = 0; ch < 16; ++ch) {
        // (a): H chunk -> HT, thread = row
        #pragma unroll
        for (int dl = 0; dl < 16; ++dl) {
            float4 cc = *(const float4*)&wp1c[ch * 16 + dl][0];
            float hh = fmaxf(px0 * cc.x + py0 * cc.y + pz0 * cc.z + cc.w, 0.f);
            hwbuf[dl * 520 + t] = f2bf(hh);
        }
        // (c) previous chunk
        if (ch > 0) {
            int dc = (ch - 1) * 16;
            #pragma unroll
            for (int qq = 0; qq < 4; ++qq) {
                int g = gq + qq;
                short8 a = z8, b = z8;
                if (h < 2) {
                    a = *(const short8*)&hwbuf[8320 + (g * 32 + 16 * m2 + ln) * 16 + 8 * h];
                    b = *(const short8*)&wp2bft[(16 * g + ln) * C + dc + 8 * h];
                }
                cacc[qq] = __builtin_amdgcn_mfma_f32_16x16x32_bf16(a, b, cacc[qq], 0, 0, 0);
            }
        }
        __syncthreads();
        // (b): Hw[g][d] = sum_k wt[g][k] * H[p*16+k][d]  (K=16 zero-padded)
        #pragma unroll
        for (int q = 0; q < 4; ++q) {
            int p = 4 * wv + q;
            short8 b = z8;
            if (h < 2) b = *(const short8*)&hwbuf[ln * 520 + p * 16 + 8 * h];
            f32x4 hw = __builtin_amdgcn_mfma_f32_16x16x32_bf16(awt[q], b, (f32x4){0.f, 0.f, 0.f, 0.f}, 0, 0, 0);
            #pragma unroll
            for (int reg = 0; reg < 4; ++reg)
                hwbuf[8320 + ((4 * h + reg) * 32 + p) * 16 + ln] = f2bf(hw[reg]);
        }
        __syncthreads();
    }
    {   // final (c), ch = 15
        int dc = 15 * 16;
        #pragma unroll
        for (int qq = 0; qq < 4; ++qq) {
            int g = gq + qq;
            short8 a = z8, b = z8;
            if (h < 2) {
                a = *(const short8*)&hwbuf[8320 + (g * 32 + 16 * m2 + ln) * 16 + 8 * h];
                b = *(const short8*)&wp2bft[(16 * g + ln) * C + dc + 8 * h];
            }
            cacc[qq] = __builtin_amdgcn_mfma_f32_16x16x32_bf16(a, b, cacc[qq], 0, 0, 0);
        }
    }

    // ---- peb -> LDS (overlay), then coalesced gather epilogue
    __syncthreads();   // all waves done reading Hw2
    float (*pebs)[256] = (float (*)[256])(void*)hwbuf;
    #pragma unroll
    for (int qq = 0; qq < 4; ++qq) {
        int g = gq + qq;
        #pragma unroll
        for (int reg = 0; reg < 4; ++reg) {
            int p = 16 * m2 + 4 * h + reg;
            pebs[p][16 * g + ln] = cacc[qq][reg];
        }
    }
    __syncthreads();

    {   // thread = (point p_e, group g_e) -> 16 consecutive channels
        const int p_e = t >> 4, g_e = t & 15, c0 = g_e * 16;
        float o[16];
        #pragma unroll
        for (int j = 0; j < 16; ++j) o[j] = pebs[p_e][c0 + j];
        {
            float wsumv = bf2f(wt_l[p_e][g_e][16]);
            float4 b0 = *(const float4*)&bp2[c0];
            float4 b1 = *(const float4*)&bp2[c0 + 4];
            float4 b2 = *(const float4*)&bp2[c0 + 8];
            float4 b3 = *(const float4*)&bp2[c0 + 12];
            o[0] += wsumv * b0.x; o[1] += wsumv * b0.y; o[2] += wsumv * b0.z; o[3] += wsumv * b0.w;
            o[4] += wsumv * b1.x; o[5] += wsumv * b1.y; o[6] += wsumv * b1.z; o[7] += wsumv * b1.w;
            o[8] += wsumv * b2.x; o[9] += wsumv * b2.y; o[10] += wsumv * b2.z; o[11] += wsumv * b2.w;
            o[12] += wsumv * b3.x; o[13] += wsumv * b3.y; o[14] += wsumv * b3.z; o[15] += wsumv * b3.w;
        }
        #pragma unroll
        for (int k = 0; k < KNN; ++k) {
            int sf = safe_s[p_e * 16 + k];
            float w = bf2f(wt_l[p_e][g_e][k]);
            uint4 va = *(const uint4*)&vb[sf * C + c0];
            uint4 vc = *(const uint4*)&vb[sf * C + c0 + 8];
            o[0]  += w * bf2f(va.x); o[1]  += w * bf2f(va.x >> 16);
            o[2]  += w * bf2f(va.y); o[3]  += w * bf2f(va.y >> 16);
            o[4]  += w * bf2f(va.z); o[5]  += w * bf2f(va.z >> 16);
            o[6]  += w * bf2f(va.w); o[7]  += w * bf2f(va.w >> 16);
            o[8]  += w * bf2f(vc.x); o[9]  += w * bf2f(vc.x >> 16);
            o[10] += w * bf2f(vc.y); o[11] += w * bf2f(vc.y >> 16);
            o[12] += w * bf2f(vc.z); o[13] += w * bf2f(vc.z >> 16);
            o[14] += w * bf2f(vc.w); o[15] += w * bf2f(vc.w >> 16);
        }
        float* op = &out[(n0 + p_e) * C + c0];
        *(float4*)&op[0]  = make_float4(o[0], o[1], o[2], o[3]);
        *(float4*)&op[4]  = make_float4(o[4], o[5], o[6], o[7]);
        *(float4*)&op[8]  = make_float4(o[8], o[9], o[10], o[11]);
        *(float4*)&op[12] = make_float4(o[12], o[13], o[14], o[15]);
    }
}

extern "C" void kernel_launch(void* const* d_in, const int* in_sizes, int n_in,
                              void* d_out, int out_size, void* d_ws, size_t ws_size,
                              hipStream_t stream) {
    const float* feat  = (const float*)d_in[0];
    const float* coord = (const float*)d_in[1];
    const int*   knn   = (const int*)d_in[2];
    const float* Wq  = (const float*)d_in[3];
    const float* bq  = (const float*)d_in[4];
    const float* bnq = (const float*)d_in[5];
    const float* Wk  = (const float*)d_in[6];
    const float* bk  = (const float*)d_in[7];
    const float* bnk = (const float*)d_in[8];
    const float* Wv  = (const float*)d_in[9];
    const float* bv  = (const float*)d_in[10];
    const float* Wp1 = (const float*)d_in[11];
    const float* bp1 = (const float*)d_in[12];
    const float* bnp = (const float*)d_in[13];
    const float* Wp2 = (const float*)d_in[14];
    const float* bp2 = (const float*)d_in[15];
    const float* Ww1 = (const float*)d_in[16];
    const float* bw1 = (const float*)d_in[17];
    const float* bnw = (const float*)d_in[18];
    const float* Ww2 = (const float*)d_in[19];
    const float* bw2 = (const float*)d_in[20];

    float* ws = (float*)d_ws;
    unsigned short* q_ws = (unsigned short*)ws;                  // 5.12M bf16
    unsigned short* k_ws = (unsigned short*)(ws + 2560000);      // 5.12M bf16
    unsigned short* v_ws = (unsigned short*)(ws + 5120000);      // 5.12M bf16
    float* qw1   = ws + 7680000;
    float* kw1   = ws + 8080000;
    float* w2w1  = ws + 8480000;
    float* c1    = ws + 8484096;
    unsigned short* wp2bft = (unsigned short*)(ws + 8500000);    // 65536 bf16
    float* outp  = (float*)d_out;

    hipLaunchKernelGGL(k_prep, dim3(257), dim3(256), 0, stream,
                       Wp2, bp2, Ww1, bw1, w2w1, c1, wp2bft);
    hipLaunchKernelGGL(k_qkv, dim3(157, 1, 3), dim3(512), 0, stream,
                       feat, Wq, bq, bnq, Wk, bk, bnk, Wv, bv, q_ws, k_ws, v_ws);
    hipLaunchKernelGGL(k_qkw, dim3(1250, 2), dim3(256), 0, stream,
                       q_ws, k_ws, Ww1, qw1, kw1);
    hipLaunchKernelGGL(k_attn, dim3(625), dim3(512), 0, stream,
                       coord, knn, Wp1, bp1, bnp, bp2, Ww2, bw2, bnw,
                       w2w1, c1, qw1, kw1, v_ws, wp2bft, outp);
}

// Round 8
// 193.216 us; speedup vs baseline: 3.5901x; 1.0918x over previous
//
#include <hip/hip_runtime.h>
#include <hip/hip_bf16.h>

#define N_PTS 20000
#define KNN 16
#define C 256
#define G 16
#define EPS 1e-5f
#define NP 16

typedef __attribute__((ext_vector_type(8))) short short8;
typedef __attribute__((ext_vector_type(4))) float f32x4;

__device__ inline unsigned short f2bf(float f) {
    unsigned int x = __float_as_uint(f);
    unsigned int r = (x + 0x7fffu + ((x >> 16) & 1u)) >> 16;
    return (unsigned short)r;
}
__device__ inline float bf2f(unsigned int u) {
    return __uint_as_float((u & 0xffffu) << 16);
}
__device__ inline short f2bfs(float f) { return (short)f2bf(f); }

// ---------------- K0: w2w1[d][g] = Wp2@Ww1; c1 = bp2@Ww1 + bw1; Wp2bfT[c][d] = bf16(Wp2[d][c])
__global__ __launch_bounds__(256) void k_prep(const float* Wp2, const float* bp2,
                                              const float* Ww1, const float* bw1,
                                              float* w2w1, float* c1,
                                              unsigned short* wp2bft) {
    __shared__ float red[256][17];
    int t = threadIdx.x, b = blockIdx.x;
    float src = (b < C) ? Wp2[b * C + t] : bp2[t];
    #pragma unroll
    for (int g = 0; g < G; ++g) red[t][g] = src * Ww1[t * G + g];
    __syncthreads();
    for (int s = 128; s > 0; s >>= 1) {
        if (t < s) {
            #pragma unroll
            for (int g = 0; g < G; ++g) red[t][g] += red[t + s][g];
        }
        __syncthreads();
    }
    if (t < G) {
        if (b < C) w2w1[b * G + t] = red[0][t];
        else       c1[t] = red[0][t] + bw1[t];
    }
    if (b < C) wp2bft[t * C + b] = f2bf(Wp2[b * C + t]);
}

// ---------------- K1: q/k/v = feat @ W via bf16 MFMA (+bias, +BN+ReLU for q,k); all outputs bf16
__global__ __launch_bounds__(512, 2) void k_qkv(
    const float* __restrict__ feat,
    const float* __restrict__ Wq, const float* __restrict__ bq, const float* __restrict__ bnq,
    const float* __restrict__ Wk, const float* __restrict__ bk, const float* __restrict__ bnk,
    const float* __restrict__ Wv, const float* __restrict__ bv,
    unsigned short* __restrict__ q_out, unsigned short* __restrict__ k_out,
    unsigned short* __restrict__ v_out) {
    __shared__ __align__(16) unsigned short Asl[128][40];   // [m][k] bf16, pad 8
    __shared__ __align__(16) unsigned short Bsl[256][40];   // [n][k] bf16, pad 8

    const int t = threadIdx.x;
    const int m0 = blockIdx.x * 128;
    const int z = blockIdx.z;
    const float* W    = (z == 0) ? Wq : (z == 1) ? Wk : Wv;
    const float* bias = (z == 0) ? bq : (z == 1) ? bk : bv;
    const float* bn   = (z == 0) ? bnq : bnk;

    const int wv = t >> 6, lane = t & 63, h = lane >> 4, ln = lane & 15;
    const int wm = wv >> 2, wn = wv & 3;

    f32x4 acc[4][4];
    #pragma unroll
    for (int i = 0; i < 4; ++i)
        #pragma unroll
        for (int j = 0; j < 4; ++j) acc[i][j] = (f32x4){0.f, 0.f, 0.f, 0.f};

    const int ar = t >> 3, ak = (t & 7) * 4;
    const int bk_n = (t & 63) * 4, bk_k = t >> 6;

    for (int kb = 0; kb < C; kb += 32) {
        #pragma unroll
        for (int ps = 0; ps < 2; ++ps) {
            int r = ar + 64 * ps;
            int gm = m0 + r; if (gm > N_PTS - 1) gm = N_PTS - 1;
            float4 f = *(const float4*)&feat[gm * C + kb + ak];
            unsigned int u0 = f2bf(f.x) | ((unsigned int)f2bf(f.y) << 16);
            unsigned int u1 = f2bf(f.z) | ((unsigned int)f2bf(f.w) << 16);
            *(uint2*)&Asl[r][ak] = make_uint2(u0, u1);
        }
        #pragma unroll
        for (int ps = 0; ps < 4; ++ps) {
            int kk = bk_k + 8 * ps;
            float4 w = *(const float4*)&W[(kb + kk) * C + bk_n];
            Bsl[bk_n + 0][kk] = f2bf(w.x);
            Bsl[bk_n + 1][kk] = f2bf(w.y);
            Bsl[bk_n + 2][kk] = f2bf(w.z);
            Bsl[bk_n + 3][kk] = f2bf(w.w);
        }
        __syncthreads();
        short8 af[4], bf[4];
        #pragma unroll
        for (int mf = 0; mf < 4; ++mf) af[mf] = *(const short8*)&Asl[64 * wm + 16 * mf + ln][8 * h];
        #pragma unroll
        for (int nf = 0; nf < 4; ++nf) bf[nf] = *(const short8*)&Bsl[64 * wn + 16 * nf + ln][8 * h];
        #pragma unroll
        for (int mf = 0; mf < 4; ++mf)
            #pragma unroll
            for (int nf = 0; nf < 4; ++nf)
                acc[mf][nf] = __builtin_amdgcn_mfma_f32_16x16x32_bf16(af[mf], bf[nf], acc[mf][nf], 0, 0, 0);
        __syncthreads();
    }

    unsigned short* dst = (z == 0) ? q_out : (z == 1) ? k_out : v_out;
    float scv[4], shv[4];
    int cidx[4];
    #pragma unroll
    for (int nf = 0; nf < 4; ++nf) {
        int c = 64 * wn + 16 * nf + ln;
        cidx[nf] = c;
        float bi = bias[c];
        if (z < 2) {
            float ga = bn[c], be = bn[C + c], mu = bn[2 * C + c], va = bn[3 * C + c];
            float s = ga * rsqrtf(va + EPS);
            scv[nf] = s; shv[nf] = (bi - mu) * s + be;
        } else { scv[nf] = 1.f; shv[nf] = bi; }
    }
    #pragma unroll
    for (int mf = 0; mf < 4; ++mf) {
        #pragma unroll
        for (int reg = 0; reg < 4; ++reg) {
            int m = m0 + 64 * wm + 16 * mf + 4 * h + reg;
            if (m >= N_PTS) continue;
            #pragma unroll
            for (int nf = 0; nf < 4; ++nf) {
                float x = acc[mf][nf][reg] * scv[nf] + shv[nf];
                if (z < 2) x = fmaxf(x, 0.f);
                dst[m * C + cidx[nf]] = f2bf(x);
            }
        }
    }
}

// ---------------- K2: qw1 = q @ Ww1, kw1 = k @ Ww1  (bf16 inputs)
__global__ __launch_bounds__(256) void k_qkw(const unsigned short* q_ws, const unsigned short* k_ws,
                                             const float* Ww1, float* qw1, float* kw1) {
    __shared__ float tile[16][260];
    __shared__ float wT[G][260];
    int t = threadIdx.x;
    const unsigned short* src = blockIdx.y ? k_ws : q_ws;
    float* dst = blockIdx.y ? kw1 : qw1;
    int r0 = blockIdx.x * 16;
    #pragma unroll
    for (int i = 0; i < 16; ++i) {
        int e = t + 256 * i;
        wT[e & 15][e >> 4] = Ww1[e];
    }
    #pragma unroll
    for (int i = 0; i < 4; ++i) {
        int e4 = t + 256 * i;
        int row = e4 >> 6, col = (e4 & 63) * 4;
        uint2 u = *(const uint2*)&src[(r0 + row) * C + col];
        tile[row][col + 0] = bf2f(u.x);
        tile[row][col + 1] = bf2f(u.x >> 16);
        tile[row][col + 2] = bf2f(u.y);
        tile[row][col + 3] = bf2f(u.y >> 16);
    }
    __syncthreads();
    int r = t >> 4, g = t & 15;
    float acc = 0.f;
    for (int c = 0; c < C; c += 4) {
        float4 a = *(float4*)&tile[r][c];
        float4 w = *(float4*)&wT[g][c];
        acc += a.x * w.x + a.y * w.y + a.z * w.z + a.w * w.w;
    }
    dst[(r0 + r) * G + g] = acc;
}

// ---------------- K3: fused MFMA attention, 16 points / 256 threads / 4 waves
// LDS ~34 KB -> 4 blocks/CU. hwbuf overlay (shorts, 8320 total):
//   phase B/C : w2w1T[16][264] @0 (4224) | Ww2T[16][16] @4224 (256) | w1s[4][16][24] @4480 (1536)
//   chunk loop: HT[16][264] @0 (4224)    | Hw2[16][16][16] @4224 (4096)
//   epilogue  : pebs f32[16][256] @0 (16384 B = 8192 shorts)
__global__ __launch_bounds__(256, 4) void k_attn(
    const float* __restrict__ coord, const int* __restrict__ knn,
    const float* __restrict__ Wp1, const float* __restrict__ bp1, const float* __restrict__ bnp,
    const float* __restrict__ bp2,
    const float* __restrict__ Ww2, const float* __restrict__ bw2, const float* __restrict__ bnw,
    const float* __restrict__ w2w1, const float* __restrict__ c1,
    const float* __restrict__ qw1, const float* __restrict__ kw1,
    const unsigned short* __restrict__ vb, const unsigned short* __restrict__ wp2bft,
    float* __restrict__ out)
{
    __shared__ __align__(16) int   safe_s[256];               // 1 KB
    __shared__ __align__(16) float wp1c[256][4];              // 4 KB
    __shared__ __align__(16) unsigned short wt_l[16][16][24]; // 12 KB  [p][g][k], k=16 -> wsum
    __shared__ __align__(16) unsigned short hwbuf[8320];      // 16.6 KB multi-use

    const int t = threadIdx.x;
    const int n0 = blockIdx.x * NP;
    const int wv = t >> 6, lane = t & 63, h = lane >> 4, ln = lane & 15;
    const short8 z8 = (short8){0, 0, 0, 0, 0, 0, 0, 0};

    float scwv, shwv, bw2v, c1v;
    {
        float ga = bnw[ln], be = bnw[G + ln], mu = bnw[2 * G + ln], va = bnw[3 * G + ln];
        scwv = ga * rsqrtf(va + EPS);
        shwv = be - mu * scwv;
        bw2v = bw2[ln];
        c1v  = c1[ln];
    }

    // ---- stage: w2w1T + Ww2T into hwbuf, wp1c
    #pragma unroll
    for (int i = 0; i < 16; ++i) {
        int e = t + 256 * i;                       // 4096 = 256 d x 16 g
        hwbuf[(e & 15) * 264 + (e >> 4)] = f2bf(w2w1[e]);
    }
    {
        float ga = bnp[t], be = bnp[C + t], mu = bnp[2 * C + t], va = bnp[3 * C + t];
        float s = ga * rsqrtf(va + EPS);
        wp1c[t][0] = Wp1[t] * s;
        wp1c[t][1] = Wp1[C + t] * s;
        wp1c[t][2] = Wp1[2 * C + t] * s;
        wp1c[t][3] = (bp1[t] - mu) * s + be;
        hwbuf[4224 + (t & 15) * 16 + (t >> 4)] = f2bf(Ww2[t]);  // Ww2T[g'][g]
    }
    // ---- per-thread pos/mask/safe (row = t)
    float px0, py0, pz0, mk0; int safe0;
    {
        const int n = n0 + (t >> 4);
        int ii = knn[n * KNN + (t & 15)];
        mk0 = (ii >= 0) ? 1.f : 0.f;
        safe0 = ii < 0 ? 0 : ii;
        safe_s[t] = safe0;
        px0 = (coord[safe0 * 3]     - coord[n * 3])     * mk0;
        py0 = (coord[safe0 * 3 + 1] - coord[n * 3 + 1]) * mk0;
        pz0 = (coord[safe0 * 3 + 2] - coord[n * 3 + 2]) * mk0;
    }
    __syncthreads();

    // ---- per-wave row pos via shfl (rows 64wv..64wv+63 are wave-private)
    float prx[4], pry[4], prz[4];
    #pragma unroll
    for (int q = 0; q < 4; ++q) {
        int src = 16 * q + ln;
        prx[q] = __shfl(px0, src, 64);
        pry[q] = __shfl(py0, src, 64);
        prz[q] = __shfl(pz0, src, 64);
    }

    // ---- phase B: w1acc = H @ w2w1 (MFMA, A in-flight)
    f32x4 accB[4];
    #pragma unroll
    for (int q = 0; q < 4; ++q) accB[q] = (f32x4){0.f, 0.f, 0.f, 0.f};
    for (int ks = 0; ks < 8; ++ks) {
        int d0 = ks * 32 + h * 8;
        float4 wpc[8];
        #pragma unroll
        for (int j = 0; j < 8; ++j) wpc[j] = *(const float4*)&wp1c[d0 + j][0];
        short8 bfr = *(const short8*)&hwbuf[ln * 264 + d0];
        #pragma unroll
        for (int q = 0; q < 4; ++q) {
            short8 afr;
            #pragma unroll
            for (int j = 0; j < 8; ++j) {
                float hh = fmaxf(prx[q] * wpc[j].x + pry[q] * wpc[j].y + prz[q] * wpc[j].z + wpc[j].w, 0.f);
                afr[j] = f2bfs(hh);
            }
            accB[q] = __builtin_amdgcn_mfma_f32_16x16x32_bf16(afr, bfr, accB[q], 0, 0, 0);
        }
    }

    // ---- phase C: BN+ReLU+offs -> w1 (bf16, wave-private LDS transpose) -> MFMA w2 -> softmax -> wt
    #pragma unroll
    for (int q = 0; q < 4; ++q) {
        const int p = 4 * wv + q;
        float mkq[4]; int sfq[4];
        #pragma unroll
        for (int reg = 0; reg < 4; ++reg) {
            int src = 16 * q + 4 * h + reg;
            mkq[reg] = __shfl(mk0, src, 64);
            sfq[reg] = __shfl(safe0, src, 64);
        }
        #pragma unroll
        for (int reg = 0; reg < 4; ++reg) {
            float kv = kw1[sfq[reg] * G + ln];
            float qv = qw1[(n0 + p) * G + ln];
            float x = accB[q][reg] + kv * mkq[reg] - qv + c1v;
            float w1 = fmaxf(scwv * x + shwv, 0.f);
            hwbuf[4480 + wv * 384 + (4 * h + reg) * 24 + ln] = f2bf(w1);  // w1s[k][g]
        }
        short8 a = z8, b = z8;
        if (h < 2) {
            a = *(const short8*)&hwbuf[4480 + wv * 384 + ln * 24 + 8 * h];  // A[k=ln][g=8h+j]
            b = *(const short8*)&hwbuf[4224 + ln * 16 + 8 * h];             // B[g'=ln][g=8h+j]
        }
        f32x4 w2v4 = __builtin_amdgcn_mfma_f32_16x16x32_bf16(
            a, b, (f32x4){bw2v, bw2v, bw2v, bw2v}, 0, 0, 0);
        float w2r[4] = {w2v4[0], w2v4[1], w2v4[2], w2v4[3]};
        // softmax over k = 4h+reg (rows), per g' = ln
        float m = fmaxf(fmaxf(w2r[0], w2r[1]), fmaxf(w2r[2], w2r[3]));
        m = fmaxf(m, __shfl_xor(m, 16, 64));
        m = fmaxf(m, __shfl_xor(m, 32, 64));
        float e4[4], s = 0.f;
        #pragma unroll
        for (int reg = 0; reg < 4; ++reg) { e4[reg] = __expf(w2r[reg] - m); s += e4[reg]; }
        s += __shfl_xor(s, 16, 64);
        s += __shfl_xor(s, 32, 64);
        float inv = 1.f / s;
        float ws4 = 0.f;
        #pragma unroll
        for (int reg = 0; reg < 4; ++reg) {
            float wt = e4[reg] * inv * mkq[reg];
            ws4 += wt;
            wt_l[p][ln][4 * h + reg] = f2bf(wt);
        }
        ws4 += __shfl_xor(ws4, 16, 64);
        ws4 += __shfl_xor(ws4, 32, 64);
        if (h == 0) wt_l[p][ln][16] = f2bf(ws4);
    }

    __syncthreads();   // phase-B/C hwbuf region dead; safe to reuse as HT/Hw2

    // ---- chunk loop: (a) H->HT ; (c)(ch-1) ; bar ; (b) wt x HT -> Hw2 ; bar
    short8 awt[4];     // loop-invariant (b) A-fragments
    #pragma unroll
    for (int q = 0; q < 4; ++q)
        awt[q] = (h < 2) ? *(const short8*)&wt_l[4 * wv + q][ln][8 * h] : z8;

    const int gq = 4 * wv;
    f32x4 cacc[4];
    #pragma unroll
    for (int qq = 0; qq < 4; ++qq) cacc[qq] = (f32x4){0.f, 0.f, 0.f, 0.f};

    for (int ch = 0; ch < 16; ++ch) {
        // (a): H chunk -> HT[16 d][256 rows], thread = row
        #pragma unroll
        for (int dl = 0; dl < 16; ++dl) {
            float4 cc = *(const float4*)&wp1c[ch * 16 + dl][0];
            float hh = fmaxf(px0 * cc.x + py0 * cc.y + pz0 * cc.z + cc.w, 0.f);
            hwbuf[dl * 264 + t] = f2bf(hh);
        }
        // (c) previous chunk: peb[m=16 points][n=16 ch of g] += Hw2 x Wp2
        if (ch > 0) {
            int dc = (ch - 1) * 16;
            #pragma unroll
            for (int qq = 0; qq < 4; ++qq) {
                int g = gq + qq;
                short8 a = z8, b = z8;
                if (h < 2) {
                    a = *(const short8*)&hwbuf[4224 + g * 256 + ln * 16 + 8 * h];
                    b = *(const short8*)&wp2bft[(16 * g + ln) * C + dc + 8 * h];
                }
                cacc[qq] = __builtin_amdgcn_mfma_f32_16x16x32_bf16(a, b, cacc[qq], 0, 0, 0);
            }
        }
        __syncthreads();
        // (b): Hw[g][d] = sum_k wt[g][k] * H[p*16+k][d]  (K=16 zero-padded)
        #pragma unroll
        for (int q = 0; q < 4; ++q) {
            int p = 4 * wv + q;
            short8 b = z8;
            if (h < 2) b = *(const short8*)&hwbuf[ln * 264 + p * 16 + 8 * h];
            f32x4 hw = __builtin_amdgcn_mfma_f32_16x16x32_bf16(awt[q], b, (f32x4){0.f, 0.f, 0.f, 0.f}, 0, 0, 0);
            #pragma unroll
            for (int reg = 0; reg < 4; ++reg)
                hwbuf[4224 + (4 * h + reg) * 256 + p * 16 + ln] = f2bf(hw[reg]);
        }
        __syncthreads();
    }
    {   // final (c), ch = 15
        int dc = 15 * 16;
        #pragma unroll
        for (int qq = 0; qq < 4; ++qq) {
            int g = gq + qq;
            short8 a = z8, b = z8;
            if (h < 2) {
                a = *(const short8*)&hwbuf[4224 + g * 256 + ln * 16 + 8 * h];
                b = *(const short8*)&wp2bft[(16 * g + ln) * C + dc + 8 * h];
            }
            cacc[qq] = __builtin_amdgcn_mfma_f32_16x16x32_bf16(a, b, cacc[qq], 0, 0, 0);
        }
    }

    // ---- peb -> LDS (overlay), then coalesced gather epilogue
    __syncthreads();   // all waves done reading Hw2
    float (*pebs)[256] = (float (*)[256])(void*)hwbuf;
    #pragma unroll
    for (int qq = 0; qq < 4; ++qq) {
        int g = gq + qq;
        #pragma unroll
        for (int reg = 0; reg < 4; ++reg) {
            int p = 4 * h + reg;                  // (c) D row = point
            pebs[p][16 * g + ln] = cacc[qq][reg];
        }
    }
    __syncthreads();

    {   // thread = (point p_e, group g_e) -> 16 consecutive channels
        const int p_e = t >> 4, g_e = t & 15, c0 = g_e * 16;
        float o[16];
        #pragma unroll
        for (int j = 0; j < 16; ++j) o[j] = pebs[p_e][c0 + j];
        {
            float wsumv = bf2f(wt_l[p_e][g_e][16]);
            float4 b0 = *(const float4*)&bp2[c0];
            float4 b1 = *(const float4*)&bp2[c0 + 4];
            float4 b2 = *(const float4*)&bp2[c0 + 8];
            float4 b3 = *(const float4*)&bp2[c0 + 12];
            o[0] += wsumv * b0.x; o[1] += wsumv * b0.y; o[2] += wsumv * b0.z; o[3] += wsumv * b0.w;
            o[4] += wsumv * b1.x; o[5] += wsumv * b1.y; o[6] += wsumv * b1.z; o[7] += wsumv * b1.w;
            o[8] += wsumv * b2.x; o[9] += wsumv * b2.y; o[10] += wsumv * b2.z; o[11] += wsumv * b2.w;
            o[12] += wsumv * b3.x; o[13] += wsumv * b3.y; o[14] += wsumv * b3.z; o[15] += wsumv * b3.w;
        }
        #pragma unroll
        for (int k = 0; k < KNN; ++k) {
            int sf = safe_s[p_e * 16 + k];
            float w = bf2f(wt_l[p_e][g_e][k]);
            uint4 va = *(const uint4*)&vb[sf * C + c0];
            uint4 vc = *(const uint4*)&vb[sf * C + c0 + 8];
            o[0]  += w * bf2f(va.x); o[1]  += w * bf2f(va.x >> 16);
            o[2]  += w * bf2f(va.y); o[3]  += w * bf2f(va.y >> 16);
            o[4]  += w * bf2f(va.z); o[5]  += w * bf2f(va.z >> 16);
            o[6]  += w * bf2f(va.w); o[7]  += w * bf2f(va.w >> 16);
            o[8]  += w * bf2f(vc.x); o[9]  += w * bf2f(vc.x >> 16);
            o[10] += w * bf2f(vc.y); o[11] += w * bf2f(vc.y >> 16);
            o[12] += w * bf2f(vc.z); o[13] += w * bf2f(vc.z >> 16);
            o[14] += w * bf2f(vc.w); o[15] += w * bf2f(vc.w >> 16);
        }
        float* op = &out[(n0 + p_e) * C + c0];
        *(float4*)&op[0]  = make_float4(o[0], o[1], o[2], o[3]);
        *(float4*)&op[4]  = make_float4(o[4], o[5], o[6], o[7]);
        *(float4*)&op[8]  = make_float4(o[8], o[9], o[10], o[11]);
        *(float4*)&op[12] = make_float4(o[12], o[13], o[14], o[15]);
    }
}

extern "C" void kernel_launch(void* const* d_in, const int* in_sizes, int n_in,
                              void* d_out, int out_size, void* d_ws, size_t ws_size,
                              hipStream_t stream) {
    const float* feat  = (const float*)d_in[0];
    const float* coord = (const float*)d_in[1];
    const int*   knn   = (const int*)d_in[2];
    const float* Wq  = (const float*)d_in[3];
    const float* bq  = (const float*)d_in[4];
    const float* bnq = (const float*)d_in[5];
    const float* Wk  = (const float*)d_in[6];
    const float* bk  = (const float*)d_in[7];
    const float* bnk = (const float*)d_in[8];
    const float* Wv  = (const float*)d_in[9];
    const float* bv  = (const float*)d_in[10];
    const float* Wp1 = (const float*)d_in[11];
    const float* bp1 = (const float*)d_in[12];
    const float* bnp = (const float*)d_in[13];
    const float* Wp2 = (const float*)d_in[14];
    const float* bp2 = (const float*)d_in[15];
    const float* Ww1 = (const float*)d_in[16];
    const float* bw1 = (const float*)d_in[17];
    const float* bnw = (const float*)d_in[18];
    const float* Ww2 = (const float*)d_in[19];
    const float* bw2 = (const float*)d_in[20];

    float* ws = (float*)d_ws;
    unsigned short* q_ws = (unsigned short*)ws;                  // 5.12M bf16
    unsigned short* k_ws = (unsigned short*)(ws + 2560000);      // 5.12M bf16
    unsigned short* v_ws = (unsigned short*)(ws + 5120000);      // 5.12M bf16
    float* qw1   = ws + 7680000;
    float* kw1   = ws + 8080000;
    float* w2w1  = ws + 8480000;
    float* c1    = ws + 8484096;
    unsigned short* wp2bft = (unsigned short*)(ws + 8500000);    // 65536 bf16
    float* outp  = (float*)d_out;

    hipLaunchKernelGGL(k_prep, dim3(257), dim3(256), 0, stream,
                       Wp2, bp2, Ww1, bw1, w2w1, c1, wp2bft);
    hipLaunchKernelGGL(k_qkv, dim3(157, 1, 3), dim3(512), 0, stream,
                       feat, Wq, bq, bnq, Wk, bk, bnk, Wv, bv, q_ws, k_ws, v_ws);
    hipLaunchKernelGGL(k_qkw, dim3(1250, 2), dim3(256), 0, stream,
                       q_ws, k_ws, Ww1, qw1, kw1);
    hipLaunchKernelGGL(k_attn, dim3(1250), dim3(256), 0, stream,
                       coord, knn, Wp1, bp1, bnp, bp2, Ww2, bw2, bnw,
                       w2w1, c1, qw1, kw1, v_ws, wp2bft, outp);
}

// Round 9
// 177.664 us; speedup vs baseline: 3.9044x; 1.0875x over previous
//
#include <hip/hip_runtime.h>
#include <hip/hip_bf16.h>

#define N_PTS 20000
#define KNN 16
#define C 256
#define G 16
#define EPS 1e-5f
#define NP 16

typedef __attribute__((ext_vector_type(8))) short short8;
typedef __attribute__((ext_vector_type(4))) float f32x4;

__device__ inline unsigned short f2bf(float f) {
    unsigned int x = __float_as_uint(f);
    unsigned int r = (x + 0x7fffu + ((x >> 16) & 1u)) >> 16;
    return (unsigned short)r;
}
__device__ inline float bf2f(unsigned int u) {
    return __uint_as_float((u & 0xffffu) << 16);
}
__device__ inline short f2bfs(float f) { return (short)f2bf(f); }

// ---------------- K0: w2w1[d][g] = Wp2@Ww1; c1 = bp2@Ww1 + bw1; Wp2bfT[c][d] = bf16(Wp2[d][c])
__global__ __launch_bounds__(256) void k_prep(const float* Wp2, const float* bp2,
                                              const float* Ww1, const float* bw1,
                                              float* w2w1, float* c1,
                                              unsigned short* wp2bft) {
    __shared__ float red[256][17];
    int t = threadIdx.x, b = blockIdx.x;
    float src = (b < C) ? Wp2[b * C + t] : bp2[t];
    #pragma unroll
    for (int g = 0; g < G; ++g) red[t][g] = src * Ww1[t * G + g];
    __syncthreads();
    for (int s = 128; s > 0; s >>= 1) {
        if (t < s) {
            #pragma unroll
            for (int g = 0; g < G; ++g) red[t][g] += red[t + s][g];
        }
        __syncthreads();
    }
    if (t < G) {
        if (b < C) w2w1[b * G + t] = red[0][t];
        else       c1[t] = red[0][t] + bw1[t];
    }
    if (b < C) wp2bft[t * C + b] = f2bf(Wp2[b * C + t]);
}

// ---------------- K1: q/k/v = feat @ W via bf16 MFMA (+bias, +BN+ReLU for q,k); all outputs bf16
__global__ __launch_bounds__(512, 2) void k_qkv(
    const float* __restrict__ feat,
    const float* __restrict__ Wq, const float* __restrict__ bq, const float* __restrict__ bnq,
    const float* __restrict__ Wk, const float* __restrict__ bk, const float* __restrict__ bnk,
    const float* __restrict__ Wv, const float* __restrict__ bv,
    unsigned short* __restrict__ q_out, unsigned short* __restrict__ k_out,
    unsigned short* __restrict__ v_out) {
    __shared__ __align__(16) unsigned short Asl[128][40];   // [m][k] bf16, pad 8
    __shared__ __align__(16) unsigned short Bsl[256][40];   // [n][k] bf16, pad 8

    const int t = threadIdx.x;
    const int m0 = blockIdx.x * 128;
    const int z = blockIdx.z;
    const float* W    = (z == 0) ? Wq : (z == 1) ? Wk : Wv;
    const float* bias = (z == 0) ? bq : (z == 1) ? bk : bv;
    const float* bn   = (z == 0) ? bnq : bnk;

    const int wv = t >> 6, lane = t & 63, h = lane >> 4, ln = lane & 15;
    const int wm = wv >> 2, wn = wv & 3;

    f32x4 acc[4][4];
    #pragma unroll
    for (int i = 0; i < 4; ++i)
        #pragma unroll
        for (int j = 0; j < 4; ++j) acc[i][j] = (f32x4){0.f, 0.f, 0.f, 0.f};

    const int ar = t >> 3, ak = (t & 7) * 4;
    const int bk_n = (t & 63) * 4, bk_k = t >> 6;

    for (int kb = 0; kb < C; kb += 32) {
        #pragma unroll
        for (int ps = 0; ps < 2; ++ps) {
            int r = ar + 64 * ps;
            int gm = m0 + r; if (gm > N_PTS - 1) gm = N_PTS - 1;
            float4 f = *(const float4*)&feat[gm * C + kb + ak];
            unsigned int u0 = f2bf(f.x) | ((unsigned int)f2bf(f.y) << 16);
            unsigned int u1 = f2bf(f.z) | ((unsigned int)f2bf(f.w) << 16);
            *(uint2*)&Asl[r][ak] = make_uint2(u0, u1);
        }
        #pragma unroll
        for (int ps = 0; ps < 4; ++ps) {
            int kk = bk_k + 8 * ps;
            float4 w = *(const float4*)&W[(kb + kk) * C + bk_n];
            Bsl[bk_n + 0][kk] = f2bf(w.x);
            Bsl[bk_n + 1][kk] = f2bf(w.y);
            Bsl[bk_n + 2][kk] = f2bf(w.z);
            Bsl[bk_n + 3][kk] = f2bf(w.w);
        }
        __syncthreads();
        short8 af[4], bf[4];
        #pragma unroll
        for (int mf = 0; mf < 4; ++mf) af[mf] = *(const short8*)&Asl[64 * wm + 16 * mf + ln][8 * h];
        #pragma unroll
        for (int nf = 0; nf < 4; ++nf) bf[nf] = *(const short8*)&Bsl[64 * wn + 16 * nf + ln][8 * h];
        #pragma unroll
        for (int mf = 0; mf < 4; ++mf)
            #pragma unroll
            for (int nf = 0; nf < 4; ++nf)
                acc[mf][nf] = __builtin_amdgcn_mfma_f32_16x16x32_bf16(af[mf], bf[nf], acc[mf][nf], 0, 0, 0);
        __syncthreads();
    }

    unsigned short* dst = (z == 0) ? q_out : (z == 1) ? k_out : v_out;
    float scv[4], shv[4];
    int cidx[4];
    #pragma unroll
    for (int nf = 0; nf < 4; ++nf) {
        int c = 64 * wn + 16 * nf + ln;
        cidx[nf] = c;
        float bi = bias[c];
        if (z < 2) {
            float ga = bn[c], be = bn[C + c], mu = bn[2 * C + c], va = bn[3 * C + c];
            float s = ga * rsqrtf(va + EPS);
            scv[nf] = s; shv[nf] = (bi - mu) * s + be;
        } else { scv[nf] = 1.f; shv[nf] = bi; }
    }
    #pragma unroll
    for (int mf = 0; mf < 4; ++mf) {
        #pragma unroll
        for (int reg = 0; reg < 4; ++reg) {
            int m = m0 + 64 * wm + 16 * mf + 4 * h + reg;
            if (m >= N_PTS) continue;
            #pragma unroll
            for (int nf = 0; nf < 4; ++nf) {
                float x = acc[mf][nf][reg] * scv[nf] + shv[nf];
                if (z < 2) x = fmaxf(x, 0.f);
                dst[m * C + cidx[nf]] = f2bf(x);
            }
        }
    }
}

// ---------------- K2: qw1 = q @ Ww1, kw1 = k @ Ww1  (bf16 inputs)
__global__ __launch_bounds__(256) void k_qkw(const unsigned short* q_ws, const unsigned short* k_ws,
                                             const float* Ww1, float* qw1, float* kw1) {
    __shared__ float tile[16][260];
    __shared__ float wT[G][260];
    int t = threadIdx.x;
    const unsigned short* src = blockIdx.y ? k_ws : q_ws;
    float* dst = blockIdx.y ? kw1 : qw1;
    int r0 = blockIdx.x * 16;
    #pragma unroll
    for (int i = 0; i < 16; ++i) {
        int e = t + 256 * i;
        wT[e & 15][e >> 4] = Ww1[e];
    }
    #pragma unroll
    for (int i = 0; i < 4; ++i) {
        int e4 = t + 256 * i;
        int row = e4 >> 6, col = (e4 & 63) * 4;
        uint2 u = *(const uint2*)&src[(r0 + row) * C + col];
        tile[row][col + 0] = bf2f(u.x);
        tile[row][col + 1] = bf2f(u.x >> 16);
        tile[row][col + 2] = bf2f(u.y);
        tile[row][col + 3] = bf2f(u.y >> 16);
    }
    __syncthreads();
    int r = t >> 4, g = t & 15;
    float acc = 0.f;
    for (int c = 0; c < C; c += 4) {
        float4 a = *(float4*)&tile[r][c];
        float4 w = *(float4*)&wT[g][c];
        acc += a.x * w.x + a.y * w.y + a.z * w.z + a.w * w.w;
    }
    dst[(r0 + r) * G + g] = acc;
}

// ---------------- K3: fused MFMA attention, 16 points / 256 threads / 4 waves
// LDS ~34 KB. launch_bounds(256,3): reg budget ~170 -> no spill, 3 blocks/CU.
// hwbuf overlay (shorts, 8320 total):
//   phase B/C : w2w1T[16][264] @0 (4224) | Ww2T[16][16] @4224 (256) | w1s[4][16][24] @4480 (1536)
//   chunk loop: HT[16][264] @0 (4224)    | Hw2[16][16][16] @4224 (4096)
//   epilogue  : pebs f32[16][256] @0 (16384 B = 8192 shorts)
__global__ __launch_bounds__(256, 3) void k_attn(
    const float* __restrict__ coord, const int* __restrict__ knn,
    const float* __restrict__ Wp1, const float* __restrict__ bp1, const float* __restrict__ bnp,
    const float* __restrict__ bp2,
    const float* __restrict__ Ww2, const float* __restrict__ bw2, const float* __restrict__ bnw,
    const float* __restrict__ w2w1, const float* __restrict__ c1,
    const float* __restrict__ qw1, const float* __restrict__ kw1,
    const unsigned short* __restrict__ vb, const unsigned short* __restrict__ wp2bft,
    float* __restrict__ out)
{
    __shared__ __align__(16) int   safe_s[256];               // 1 KB
    __shared__ __align__(16) float wp1c[256][4];              // 4 KB
    __shared__ __align__(16) unsigned short wt_l[16][16][24]; // 12 KB  [p][g][k], k=16 -> wsum
    __shared__ __align__(16) unsigned short hwbuf[8320];      // 16.6 KB multi-use

    const int t = threadIdx.x;
    const int n0 = blockIdx.x * NP;
    const int wv = t >> 6, lane = t & 63, h = lane >> 4, ln = lane & 15;
    const short8 z8 = (short8){0, 0, 0, 0, 0, 0, 0, 0};

    float scwv, shwv, bw2v, c1v;
    {
        float ga = bnw[ln], be = bnw[G + ln], mu = bnw[2 * G + ln], va = bnw[3 * G + ln];
        scwv = ga * rsqrtf(va + EPS);
        shwv = be - mu * scwv;
        bw2v = bw2[ln];
        c1v  = c1[ln];
    }

    // ---- stage: w2w1T + Ww2T into hwbuf, wp1c
    #pragma unroll
    for (int i = 0; i < 16; ++i) {
        int e = t + 256 * i;                       // 4096 = 256 d x 16 g
        hwbuf[(e & 15) * 264 + (e >> 4)] = f2bf(w2w1[e]);
    }
    {
        float ga = bnp[t], be = bnp[C + t], mu = bnp[2 * C + t], va = bnp[3 * C + t];
        float s = ga * rsqrtf(va + EPS);
        wp1c[t][0] = Wp1[t] * s;
        wp1c[t][1] = Wp1[C + t] * s;
        wp1c[t][2] = Wp1[2 * C + t] * s;
        wp1c[t][3] = (bp1[t] - mu) * s + be;
        hwbuf[4224 + (t & 15) * 16 + (t >> 4)] = f2bf(Ww2[t]);  // Ww2T[g'][g]
    }
    // ---- per-thread pos/mask/safe (row = t)
    float px0, py0, pz0, mk0; int safe0;
    {
        const int n = n0 + (t >> 4);
        int ii = knn[n * KNN + (t & 15)];
        mk0 = (ii >= 0) ? 1.f : 0.f;
        safe0 = ii < 0 ? 0 : ii;
        safe_s[t] = safe0;
        px0 = (coord[safe0 * 3]     - coord[n * 3])     * mk0;
        py0 = (coord[safe0 * 3 + 1] - coord[n * 3 + 1]) * mk0;
        pz0 = (coord[safe0 * 3 + 2] - coord[n * 3 + 2]) * mk0;
    }
    __syncthreads();

    // ---- per-wave row pos via shfl (rows 64wv..64wv+63 are wave-private)
    float prx[4], pry[4], prz[4];
    #pragma unroll
    for (int q = 0; q < 4; ++q) {
        int src = 16 * q + ln;
        prx[q] = __shfl(px0, src, 64);
        pry[q] = __shfl(py0, src, 64);
        prz[q] = __shfl(pz0, src, 64);
    }

    // ---- phase B: w1acc = H @ w2w1 (MFMA, A in-flight)
    f32x4 accB[4];
    #pragma unroll
    for (int q = 0; q < 4; ++q) accB[q] = (f32x4){0.f, 0.f, 0.f, 0.f};
    for (int ks = 0; ks < 8; ++ks) {
        int d0 = ks * 32 + h * 8;
        float4 wpc[8];
        #pragma unroll
        for (int j = 0; j < 8; ++j) wpc[j] = *(const float4*)&wp1c[d0 + j][0];
        short8 bfr = *(const short8*)&hwbuf[ln * 264 + d0];
        #pragma unroll
        for (int q = 0; q < 4; ++q) {
            short8 afr;
            #pragma unroll
            for (int j = 0; j < 8; ++j) {
                float hh = fmaxf(prx[q] * wpc[j].x + pry[q] * wpc[j].y + prz[q] * wpc[j].z + wpc[j].w, 0.f);
                afr[j] = f2bfs(hh);
            }
            accB[q] = __builtin_amdgcn_mfma_f32_16x16x32_bf16(afr, bfr, accB[q], 0, 0, 0);
        }
    }

    // ---- phase C: BN+ReLU+offs -> w1 (bf16, wave-private LDS transpose) -> MFMA w2 -> softmax -> wt
    #pragma unroll
    for (int q = 0; q < 4; ++q) {
        const int p = 4 * wv + q;
        float mkq[4]; int sfq[4];
        #pragma unroll
        for (int reg = 0; reg < 4; ++reg) {
            int src = 16 * q + 4 * h + reg;
            mkq[reg] = __shfl(mk0, src, 64);
            sfq[reg] = __shfl(safe0, src, 64);
        }
        #pragma unroll
        for (int reg = 0; reg < 4; ++reg) {
            float kv = kw1[sfq[reg] * G + ln];
            float qv = qw1[(n0 + p) * G + ln];
            float x = accB[q][reg] + kv * mkq[reg] - qv + c1v;
            float w1 = fmaxf(scwv * x + shwv, 0.f);
            hwbuf[4480 + wv * 384 + (4 * h + reg) * 24 + ln] = f2bf(w1);  // w1s[k][g]
        }
        short8 a = z8, b = z8;
        if (h < 2) {
            a = *(const short8*)&hwbuf[4480 + wv * 384 + ln * 24 + 8 * h];  // A[k=ln][g=8h+j]
            b = *(const short8*)&hwbuf[4224 + ln * 16 + 8 * h];             // B[g'=ln][g=8h+j]
        }
        f32x4 w2v4 = __builtin_amdgcn_mfma_f32_16x16x32_bf16(
            a, b, (f32x4){bw2v, bw2v, bw2v, bw2v}, 0, 0, 0);
        float w2r[4] = {w2v4[0], w2v4[1], w2v4[2], w2v4[3]};
        // softmax over k = 4h+reg (rows), per g' = ln
        float m = fmaxf(fmaxf(w2r[0], w2r[1]), fmaxf(w2r[2], w2r[3]));
        m = fmaxf(m, __shfl_xor(m, 16, 64));
        m = fmaxf(m, __shfl_xor(m, 32, 64));
        float e4[4], s = 0.f;
        #pragma unroll
        for (int reg = 0; reg < 4; ++reg) { e4[reg] = __expf(w2r[reg] - m); s += e4[reg]; }
        s += __shfl_xor(s, 16, 64);
        s += __shfl_xor(s, 32, 64);
        float inv = 1.f / s;
        float ws4 = 0.f;
        #pragma unroll
        for (int reg = 0; reg < 4; ++reg) {
            float wt = e4[reg] * inv * mkq[reg];
            ws4 += wt;
            wt_l[p][ln][4 * h + reg] = f2bf(wt);
        }
        ws4 += __shfl_xor(ws4, 16, 64);
        ws4 += __shfl_xor(ws4, 32, 64);
        if (h == 0) wt_l[p][ln][16] = f2bf(ws4);
    }

    __syncthreads();   // phase-B/C hwbuf region dead; safe to reuse as HT/Hw2

    // ---- chunk loop: (a) H->HT ; (c)(ch-1) ; bar ; (b) wt x HT -> Hw2 ; bar
    short8 awt[4];     // loop-invariant (b) A-fragments
    #pragma unroll
    for (int q = 0; q < 4; ++q)
        awt[q] = (h < 2) ? *(const short8*)&wt_l[4 * wv + q][ln][8 * h] : z8;

    const int gq = 4 * wv;
    f32x4 cacc[4];
    #pragma unroll
    for (int qq = 0; qq < 4; ++qq) cacc[qq] = (f32x4){0.f, 0.f, 0.f, 0.f};

    for (int ch = 0; ch < 16; ++ch) {
        // (a): H chunk -> HT[16 d][256 rows], thread = row
        #pragma unroll
        for (int dl = 0; dl < 16; ++dl) {
            float4 cc = *(const float4*)&wp1c[ch * 16 + dl][0];
            float hh = fmaxf(px0 * cc.x + py0 * cc.y + pz0 * cc.z + cc.w, 0.f);
            hwbuf[dl * 264 + t] = f2bf(hh);
        }
        // (c) previous chunk: peb[m=16 points][n=16 ch of g] += Hw2 x Wp2
        if (ch > 0) {
            int dc = (ch - 1) * 16;
            #pragma unroll
            for (int qq = 0; qq < 4; ++qq) {
                int g = gq + qq;
                short8 a = z8, b = z8;
                if (h < 2) {
                    a = *(const short8*)&hwbuf[4224 + g * 256 + ln * 16 + 8 * h];
                    b = *(const short8*)&wp2bft[(16 * g + ln) * C + dc + 8 * h];
                }
                cacc[qq] = __builtin_amdgcn_mfma_f32_16x16x32_bf16(a, b, cacc[qq], 0, 0, 0);
            }
        }
        __syncthreads();
        // (b): Hw[g][d] = sum_k wt[g][k] * H[p*16+k][d]  (K=16 zero-padded)
        #pragma unroll
        for (int q = 0; q < 4; ++q) {
            int p = 4 * wv + q;
            short8 b = z8;
            if (h < 2) b = *(const short8*)&hwbuf[ln * 264 + p * 16 + 8 * h];
            f32x4 hw = __builtin_amdgcn_mfma_f32_16x16x32_bf16(awt[q], b, (f32x4){0.f, 0.f, 0.f, 0.f}, 0, 0, 0);
            #pragma unroll
            for (int reg = 0; reg < 4; ++reg)
                hwbuf[4224 + (4 * h + reg) * 256 + p * 16 + ln] = f2bf(hw[reg]);
        }
        __syncthreads();
    }
    {   // final (c), ch = 15
        int dc = 15 * 16;
        #pragma unroll
        for (int qq = 0; qq < 4; ++qq) {
            int g = gq + qq;
            short8 a = z8, b = z8;
            if (h < 2) {
                a = *(const short8*)&hwbuf[4224 + g * 256 + ln * 16 + 8 * h];
                b = *(const short8*)&wp2bft[(16 * g + ln) * C + dc + 8 * h];
            }
            cacc[qq] = __builtin_amdgcn_mfma_f32_16x16x32_bf16(a, b, cacc[qq], 0, 0, 0);
        }
    }

    // ---- peb -> LDS (overlay), then coalesced gather epilogue
    __syncthreads();   // all waves done reading Hw2
    float (*pebs)[256] = (float (*)[256])(void*)hwbuf;
    #pragma unroll
    for (int qq = 0; qq < 4; ++qq) {
        int g = gq + qq;
        #pragma unroll
        for (int reg = 0; reg < 4; ++reg) {
            int p = 4 * h + reg;                  // (c) D row = point
            pebs[p][16 * g + ln] = cacc[qq][reg];
        }
    }
    __syncthreads();

    {   // thread = (point p_e, group g_e) -> 16 consecutive channels
        const int p_e = t >> 4, g_e = t & 15, c0 = g_e * 16;
        float o[16];
        #pragma unroll
        for (int j = 0; j < 16; ++j) o[j] = pebs[p_e][c0 + j];
        {
            float wsumv = bf2f(wt_l[p_e][g_e][16]);
            float4 b0 = *(const float4*)&bp2[c0];
            float4 b1 = *(const float4*)&bp2[c0 + 4];
            float4 b2 = *(const float4*)&bp2[c0 + 8];
            float4 b3 = *(const float4*)&bp2[c0 + 12];
            o[0] += wsumv * b0.x; o[1] += wsumv * b0.y; o[2] += wsumv * b0.z; o[3] += wsumv * b0.w;
            o[4] += wsumv * b1.x; o[5] += wsumv * b1.y; o[6] += wsumv * b1.z; o[7] += wsumv * b1.w;
            o[8] += wsumv * b2.x; o[9] += wsumv * b2.y; o[10] += wsumv * b2.z; o[11] += wsumv * b2.w;
            o[12] += wsumv * b3.x; o[13] += wsumv * b3.y; o[14] += wsumv * b3.z; o[15] += wsumv * b3.w;
        }
        #pragma unroll
        for (int k = 0; k < KNN; ++k) {
            int sf = safe_s[p_e * 16 + k];
            float w = bf2f(wt_l[p_e][g_e][k]);
            uint4 va = *(const uint4*)&vb[sf * C + c0];
            uint4 vc = *(const uint4*)&vb[sf * C + c0 + 8];
            o[0]  += w * bf2f(va.x); o[1]  += w * bf2f(va.x >> 16);
            o[2]  += w * bf2f(va.y); o[3]  += w * bf2f(va.y >> 16);
            o[4]  += w * bf2f(va.z); o[5]  += w * bf2f(va.z >> 16);
            o[6]  += w * bf2f(va.w); o[7]  += w * bf2f(va.w >> 16);
            o[8]  += w * bf2f(vc.x); o[9]  += w * bf2f(vc.x >> 16);
            o[10] += w * bf2f(vc.y); o[11] += w * bf2f(vc.y >> 16);
            o[12] += w * bf2f(vc.z); o[13] += w * bf2f(vc.z >> 16);
            o[14] += w * bf2f(vc.w); o[15] += w * bf2f(vc.w >> 16);
        }
        float* op = &out[(n0 + p_e) * C + c0];
        *(float4*)&op[0]  = make_float4(o[0], o[1], o[2], o[3]);
        *(float4*)&op[4]  = make_float4(o[4], o[5], o[6], o[7]);
        *(float4*)&op[8]  = make_float4(o[8], o[9], o[10], o[11]);
        *(float4*)&op[12] = make_float4(o[12], o[13], o[14], o[15]);
    }
}

extern "C" void kernel_launch(void* const* d_in, const int* in_sizes, int n_in,
                              void* d_out, int out_size, void* d_ws, size_t ws_size,
                              hipStream_t stream) {
    const float* feat  = (const float*)d_in[0];
    const float* coord = (const float*)d_in[1];
    const int*   knn   = (const int*)d_in[2];
    const float* Wq  = (const float*)d_in[3];
    const float* bq  = (const float*)d_in[4];
    const float* bnq = (const float*)d_in[5];
    const float* Wk  = (const float*)d_in[6];
    const float* bk  = (const float*)d_in[7];
    const float* bnk = (const float*)d_in[8];
    const float* Wv  = (const float*)d_in[9];
    const float* bv  = (const float*)d_in[10];
    const float* Wp1 = (const float*)d_in[11];
    const float* bp1 = (const float*)d_in[12];
    const float* bnp = (const float*)d_in[13];
    const float* Wp2 = (const float*)d_in[14];
    const float* bp2 = (const float*)d_in[15];
    const float* Ww1 = (const float*)d_in[16];
    const float* bw1 = (const float*)d_in[17];
    const float* bnw = (const float*)d_in[18];
    const float* Ww2 = (const float*)d_in[19];
    const float* bw2 = (const float*)d_in[20];

    float* ws = (float*)d_ws;
    unsigned short* q_ws = (unsigned short*)ws;                  // 5.12M bf16
    unsigned short* k_ws = (unsigned short*)(ws + 2560000);      // 5.12M bf16
    unsigned short* v_ws = (unsigned short*)(ws + 5120000);      // 5.12M bf16
    float* qw1   = ws + 7680000;
    float* kw1   = ws + 8080000;
    float* w2w1  = ws + 8480000;
    float* c1    = ws + 8484096;
    unsigned short* wp2bft = (unsigned short*)(ws + 8500000);    // 65536 bf16
    float* outp  = (float*)d_out;

    hipLaunchKernelGGL(k_prep, dim3(257), dim3(256), 0, stream,
                       Wp2, bp2, Ww1, bw1, w2w1, c1, wp2bft);
    hipLaunchKernelGGL(k_qkv, dim3(157, 1, 3), dim3(512), 0, stream,
                       feat, Wq, bq, bnq, Wk, bk, bnk, Wv, bv, q_ws, k_ws, v_ws);
    hipLaunchKernelGGL(k_qkw, dim3(1250, 2), dim3(256), 0, stream,
                       q_ws, k_ws, Ww1, qw1, kw1);
    hipLaunchKernelGGL(k_attn, dim3(1250), dim3(256), 0, stream,
                       coord, knn, Wp1, bp1, bnp, bp2, Ww2, bw2, bnw,
                       w2w1, c1, qw1, kw1, v_ws, wp2bft, outp);
}